// Round 13
// baseline (1499.433 us; speedup 1.0000x reference)
//
#include <hip/hip_runtime.h>
#include <cstdint>
#include <cstddef>

#define M_TOK   1232      // B*S
#define M_PAD   1280
#define D_MODEL 2048
#define F_FFN   8192
#define SEQ     77
#define BATCH   16
#define NHEAD   16
#define LRANK   16
#define NLAYER  2
#define ATILE   16

typedef short bf16x8 __attribute__((ext_vector_type(8)));
typedef float f32x4  __attribute__((ext_vector_type(4)));

__device__ __constant__ float NF4C[16] = {
  -1.0f, -0.6961928009986877f, -0.5250730514526367f, -0.39491748809814453f,
  -0.28444138169288635f, -0.18477343022823334f, -0.09105003625154495f, 0.0f,
  0.07958029955625534f, 0.16093020141124725f, 0.24611230194568634f,
  0.33791524171829224f, 0.44070982933044434f, 0.5626170039176941f,
  0.723855197429657f, 1.0f };

__device__ inline unsigned short f2b(float f) {
  unsigned u = __builtin_bit_cast(unsigned, f);
  u += 0x7FFFu + ((u >> 16) & 1u);   // RNE
  return (unsigned short)(u >> 16);
}
__device__ inline float b2f(unsigned short s) {
  return __builtin_bit_cast(float, ((unsigned)s) << 16);
}

// shared carry body: materialize bf16 weights over [beg8, beg8+cnt8) 8-elem units
__device__ inline void carry_body(const float* tb, long cid, long ncb, int tid,
                                  const int* C2, const float* AM2,
                                  unsigned short* W2, int K2, long beg8,
                                  long cnt8, int ilv2) {
  const int KB2 = K2 >> 6;
  for (long i = cid * 256 + tid; i < cnt8; i += ncb * 256) {
    long e = (beg8 + i) << 3;
    int rd = (int)(e / K2), k = (int)(e - (long)rd * K2);
    int srcn = ilv2 ? ((rd & 1) * F_FFN + (rd >> 1)) : rd;
    float am = AM2[(size_t)srcn * KB2 + (k >> 6)];
    const int4* cp = (const int4*)(C2 + (size_t)srcn * K2 + (k & (K2 - 1)));
    int4 a = cp[0], b = cp[1];
    uint4 o;
    o.x = (unsigned)f2b(tb[a.x] * am) | ((unsigned)f2b(tb[a.y] * am) << 16);
    o.y = (unsigned)f2b(tb[a.z] * am) | ((unsigned)f2b(tb[a.w] * am) << 16);
    o.z = (unsigned)f2b(tb[b.x] * am) | ((unsigned)f2b(tb[b.y] * am) << 16);
    o.w = (unsigned)f2b(tb[b.z] * am) | ((unsigned)f2b(tb[b.w] * am) << 16);
    *(uint4*)(W2 + e) = o;
  }
}

// ---------------------------------------------------------------------------
// Standalone weight materialization (prologue only).
__global__ __launch_bounds__(256) void mat_w(
    const int* __restrict__ C, const float* __restrict__ AM,
    unsigned short* __restrict__ W, int K, long total8, int ilv)
{
  __shared__ float tb[16];
  if (threadIdx.x < 16) tb[threadIdx.x] = NF4C[threadIdx.x];
  __syncthreads();
  carry_body(tb, blockIdx.x, gridDim.x, threadIdx.x, C, AM, W, K, 0, total8, ilv);
}

// ---------------------------------------------------------------------------
// bf16 GEMM (m97 single-buffer 32KB) + INTERLEAVED carry blocks:
// cpat=1: odd bids carry (50%); cpat=3: (bid&3)==3 carry (25%); cpat=0: none.
// Carry blocks co-reside with GEMM blocks from t=0 and materialize the next
// weight matrix. Epilogues: +=/split-K atomics/fused LoRA-2/GUMODE.
// ---------------------------------------------------------------------------
__global__ __launch_bounds__(256, 2) void gemm_bf(
    const unsigned short* __restrict__ X, const unsigned short* __restrict__ W,
    float* __restrict__ O, int mb, int N, int K, int acc_mode, int splitk,
    const float* __restrict__ T, const float* __restrict__ Bm, int sh, int nr,
    int gum, unsigned short* __restrict__ GB,
    const int* __restrict__ C2, const float* __restrict__ AM2,
    unsigned short* __restrict__ W2, int K2, long beg8, long cnt8, int ilv2,
    int cpat, int Ggemm)
{
  __shared__ __align__(16) unsigned short xs[128 * 64];
  __shared__ __align__(16) unsigned short ws[128 * 64];

  int tid = threadIdx.x;
  int bid = blockIdx.x;

  int gemm_id = bid, cflag = 0; long cid = 0, ncb = 0;
  if (cpat == 1) {
    cflag = bid & 1; gemm_id = bid >> 1; cid = bid >> 1; ncb = gridDim.x >> 1;
  } else if (cpat == 3) {
    cflag = ((bid & 3) == 3); gemm_id = (bid >> 2) * 3 + (bid & 3);
    cid = bid >> 2; ncb = gridDim.x >> 2;
  }
  if (cflag) {
    if (cnt8 > 0) {
      float* tb = (float*)xs;
      if (tid < 16) tb[tid] = NF4C[tid];
      __syncthreads();
      carry_body(tb, cid, ncb, tid, C2, AM2, W2, K2, beg8, cnt8, ilv2);
    }
    return;
  }
  if (gemm_id >= Ggemm) return;

  // XCD-chunked bijective swizzle over the GEMM sub-grid
  int nwg = Ggemm;
  int q8 = nwg >> 3, r8 = nwg & 7;
  int xcd = gemm_id & 7, pos = gemm_id >> 3;
  int wgid = (xcd < r8) ? (xcd * (q8 + 1) + pos)
                        : (r8 * (q8 + 1) + (xcd - r8) * q8 + pos);
  int nb = N >> 7;
  int per = mb * nb;
  int slice = wgid / per; int rem = wgid - slice * per;
  int nblk = rem / mb, mblk = rem - nblk * mb;
  int row0 = mblk << 7, col0 = nblk << 7;
  int KBtot = K >> 6, kcnt = KBtot / splitk, kbeg = slice * kcnt;

  int wave = tid >> 6, lane = tid & 63;
  int fr = lane & 15, fg = lane >> 4, s7 = fr & 7;
  int wm = (wave >> 1) * 64, wn = (wave & 1) * 64;
  int xg = lane >> 3;
  int xcol = (((lane & 7) ^ (xg & 7)) << 3);

  const unsigned short* Xbase = X + (size_t)row0 * K + (size_t)kbeg * 64;
  const unsigned short* Wbase = W + (size_t)col0 * K + (size_t)kbeg * 64;

  f32x4 accm[4][4];
  #pragma unroll
  for (int i = 0; i < 4; ++i)
    #pragma unroll
    for (int j = 0; j < 4; ++j) accm[i][j] = (f32x4){0.f, 0.f, 0.f, 0.f};

  auto stage = [&](int t) {
    const unsigned short* xb = Xbase + (size_t)t * 64;
    const unsigned short* wb = Wbase + (size_t)t * 64;
    #pragma unroll
    for (int p2 = 0; p2 < 4; ++p2) {
      int c = wave * 4 + p2;
      const unsigned short* gp = xb + (size_t)(c * 8 + xg) * K + xcol;
      __builtin_amdgcn_global_load_lds(
          (const __attribute__((address_space(1))) unsigned int*)gp,
          (__attribute__((address_space(3))) unsigned int*)(xs + c * 512),
          16, 0, 0);
    }
    #pragma unroll
    for (int p2 = 0; p2 < 4; ++p2) {
      int c = wave * 4 + p2;
      const unsigned short* gp = wb + (size_t)(c * 8 + xg) * K + xcol;
      __builtin_amdgcn_global_load_lds(
          (const __attribute__((address_space(1))) unsigned int*)gp,
          (__attribute__((address_space(3))) unsigned int*)(ws + c * 512),
          16, 0, 0);
    }
  };
  auto compute = [&]() {
    bf16x8 b0[4], b1[4];
    #pragma unroll
    for (int ni = 0; ni < 4; ++ni) {
      const unsigned short* wr = ws + (wn + ni * 16 + fr) * 64;
      b0[ni] = *(const bf16x8*)(wr + ((fg ^ s7) << 3));
      b1[ni] = *(const bf16x8*)(wr + (((4 | fg) ^ s7) << 3));
    }
    #pragma unroll
    for (int mi = 0; mi < 4; ++mi) {
      const unsigned short* xr = xs + (wm + mi * 16 + fr) * 64;
      bf16x8 a0 = *(const bf16x8*)(xr + ((fg ^ s7) << 3));
      bf16x8 a1 = *(const bf16x8*)(xr + (((4 | fg) ^ s7) << 3));
      #pragma unroll
      for (int ni = 0; ni < 4; ++ni) {
        accm[mi][ni] = __builtin_amdgcn_mfma_f32_16x16x32_bf16(
            a0, b0[ni], accm[mi][ni], 0, 0, 0);
        accm[mi][ni] = __builtin_amdgcn_mfma_f32_16x16x32_bf16(
            a1, b1[ni], accm[mi][ni], 0, 0, 0);
      }
    }
  };

  stage(0);
  for (int t = 0; t < kcnt; ++t) {
    __syncthreads();
    compute();
    if (t + 1 < kcnt) {
      __syncthreads();
      stage(t + 1);
    }
  }

  if (gum) {
    // ---- GUMODE epilogue: cols interleaved gate/up; out = silu(g)*u ----
    float* Tt = (float*)&xs[0];   // 128 x 32
    float* Bt = (float*)&ws[0];   // 128 x 16 (interleaved rows)
    __syncthreads();
    for (int idx = tid; idx < 128 * 32; idx += 256) {
      int rr = idx >> 5, c = idx & 31;
      int gm = row0 + rr;
      Tt[idx] = (gm < M_TOK) ? T[(size_t)gm * 32 + c] : 0.f;
    }
    for (int idx = tid; idx < 128 * 16; idx += 256) {
      int rr = idx >> 4, c = idx & 15;
      int type = rr & 1, nrow = (col0 + rr) >> 1;
      Bt[idx] = Bm[((size_t)type * F_FFN + nrow) * LRANK + c];
    }
    __syncthreads();
    #pragma unroll
    for (int mi = 0; mi < 4; ++mi)
      #pragma unroll
      for (int ni = 0; ni < 4; ++ni) {
        int gm0 = row0 + wm + mi * 16 + fg * 4;
        int gnl = wn + ni * 16 + fr;
        #pragma unroll
        for (int r = 0; r < 4; ++r) {
          int gm = gm0 + r;
          float vv = accm[mi][ni][r];
          const float* tr = Tt + (wm + mi * 16 + fg * 4 + r) * 32 + ((gnl & 1) << 4);
          const float* br = Bt + gnl * 16;
          float s = 0.f;
          #pragma unroll
          for (int c = 0; c < 16; ++c) s += tr[c] * br[c];
          vv += 2.0f * s;
          float prt = __shfl_xor(vv, 1);
          if (gm < M_TOK && !(fr & 1)) {
            float sig = 1.0f / (1.0f + expf(-vv));
            GB[(size_t)gm * F_FFN + ((col0 + gnl) >> 1)] = f2b(vv * sig * prt);
          }
        }
      }
    return;
  }

  // fused LoRA-2 staging (slice 0 only when split-K)
  int doT = (T != nullptr) && (slice == 0);
  float* Tt = (float*)&xs[0];
  float* Bt = (float*)&ws[0];
  if (doT) {
    __syncthreads();
    int toff = (col0 >> sh) << 4;
    for (int idx = tid; idx < 128 * 16; idx += 256) {
      int rr = idx >> 4, c = idx & 15;
      int gm = row0 + rr;
      Tt[idx] = (gm < M_TOK) ? T[(size_t)gm * nr + toff + c] : 0.f;
      Bt[idx] = Bm[(size_t)(col0 + rr) * LRANK + c];
    }
    __syncthreads();
  }

  #pragma unroll
  for (int mi = 0; mi < 4; ++mi)
    #pragma unroll
    for (int ni = 0; ni < 4; ++ni) {
      int gm0 = row0 + wm + mi * 16 + fg * 4;
      int gnl = wn + ni * 16 + fr;
      int gn = col0 + gnl;
      #pragma unroll
      for (int r = 0; r < 4; ++r) {
        int gm = gm0 + r;
        if (gm < M_TOK) {
          size_t idx = (size_t)gm * N + gn;
          float vv = accm[mi][ni][r];
          if (doT) {
            const float* tr = Tt + (wm + mi * 16 + fg * 4 + r) * 16;
            const float* br = Bt + gnl * 16;
            float s = 0.f;
            #pragma unroll
            for (int c = 0; c < 16; ++c) s += tr[c] * br[c];
            vv += 2.0f * s;
          }
          if (splitk > 1)       atomicAdd(&O[idx], vv);
          else if (acc_mode)    O[idx] += vv;
          else                  O[idx] = vv;
        }
      }
    }
}

// ---------------------------------------------------------------------------
// LoRA stage 1, 4 m-rows per block
__global__ __launch_bounds__(256) void lora1(
    const unsigned short* __restrict__ X, const float* __restrict__ A,
    float* __restrict__ T, int K)
{
  int m0 = blockIdx.x * 4, bi = blockIdx.y, nmat = gridDim.y;
  int g = threadIdx.x >> 4, l16 = threadIdx.x & 15;
  const float* ar = A + (size_t)bi * LRANK * K + (size_t)g * K;
  const unsigned short* x0 = X + (size_t)m0 * K;
  float s0 = 0.f, s1 = 0.f, s2 = 0.f, s3 = 0.f;
  for (int kk = l16 * 4; kk < K; kk += 64) {
    float4 av = *(const float4*)(ar + kk);
    ushort4 v0 = *(const ushort4*)(x0 + kk);
    ushort4 v1 = *(const ushort4*)(x0 + K + kk);
    ushort4 v2 = *(const ushort4*)(x0 + 2 * K + kk);
    ushort4 v3 = *(const ushort4*)(x0 + 3 * K + kk);
    s0 += b2f(v0.x)*av.x + b2f(v0.y)*av.y + b2f(v0.z)*av.z + b2f(v0.w)*av.w;
    s1 += b2f(v1.x)*av.x + b2f(v1.y)*av.y + b2f(v1.z)*av.z + b2f(v1.w)*av.w;
    s2 += b2f(v2.x)*av.x + b2f(v2.y)*av.y + b2f(v2.z)*av.z + b2f(v2.w)*av.w;
    s3 += b2f(v3.x)*av.x + b2f(v3.y)*av.y + b2f(v3.z)*av.z + b2f(v3.w)*av.w;
  }
  #pragma unroll
  for (int off = 8; off; off >>= 1) {
    s0 += __shfl_down(s0, off, 16);
    s1 += __shfl_down(s1, off, 16);
    s2 += __shfl_down(s2, off, 16);
    s3 += __shfl_down(s3, off, 16);
  }
  if (l16 == 0) {
    size_t base = ((size_t)m0 * nmat + bi) * LRANK + g;
    size_t rs = (size_t)nmat * LRANK;
    T[base] = s0; T[base + rs] = s1; T[base + 2*rs] = s2; T[base + 3*rs] = s3;
  }
}

// LoRA stage 2 (for split-K GEMMs), 8 m-rows per block
__global__ __launch_bounds__(256) void lora2(
    float* __restrict__ O, const float* __restrict__ T,
    const float* __restrict__ Bm, int N, int sh, int nr)
{
  int m0 = blockIdx.y * 8;
  int n = blockIdx.x * 256 + threadIdx.x;
  __shared__ float ts[8 * 48];
  for (int i = threadIdx.x; i < 8 * nr; i += 256)
    ts[(i / nr) * 48 + (i % nr)] = T[(size_t)(m0 + i / nr) * nr + (i % nr)];
  __syncthreads();
  const float4* br = (const float4*)(Bm + (size_t)n * LRANK);
  float4 b0 = br[0], b1 = br[1], b2 = br[2], b3 = br[3];
  int toff = ((n >> sh) << 4);
  #pragma unroll
  for (int mi = 0; mi < 8; ++mi) {
    const float* tsb = ts + mi * 48 + toff;
    float s = b0.x*tsb[0] + b0.y*tsb[1] + b0.z*tsb[2] + b0.w*tsb[3]
            + b1.x*tsb[4] + b1.y*tsb[5] + b1.z*tsb[6] + b1.w*tsb[7]
            + b2.x*tsb[8] + b2.y*tsb[9] + b2.z*tsb[10] + b2.w*tsb[11]
            + b3.x*tsb[12] + b3.y*tsb[13] + b3.z*tsb[14] + b3.w*tsb[15];
    O[(size_t)(m0 + mi) * N + n] += 2.0f * s;
  }
}

// ---------------------------------------------------------------------------
__global__ __launch_bounds__(256) void rmsnorm_k(
    const float* __restrict__ H, const float* __restrict__ W,
    unsigned short* __restrict__ X, int D)
{
  int m = blockIdx.x;
  const float* hr = H + (size_t)m * D;
  float s = 0.f;
  for (int i = threadIdx.x; i < D; i += 256) { float v = hr[i]; s += v * v; }
  __shared__ float red[4];
  #pragma unroll
  for (int off = 32; off; off >>= 1) s += __shfl_down(s, off, 64);
  if ((threadIdx.x & 63) == 0) red[threadIdx.x >> 6] = s;
  __syncthreads();
  float tot = red[0] + red[1] + red[2] + red[3];
  float inv = rsqrtf(tot / (float)D + 1e-6f);
  for (int i = threadIdx.x; i < D; i += 256)
    X[(size_t)m * D + i] = f2b(hr[i] * inv * W[i]);
}

__global__ void rope_table(float* __restrict__ cosT, float* __restrict__ sinT)
{
  int idx = blockIdx.x * 64 + threadIdx.x;
  if (idx >= SEQ * 64) return;
  int s = idx >> 6, j = idx & 63;
  float inv = powf(10000.0f, -(float)(2 * j) / 128.0f);
  float f = (float)s * inv;
  cosT[idx] = cosf(f);
  sinT[idx] = sinf(f);
}

// ---------------------------------------------------------------------------
// Attention with fused RoPE + carry row (blockIdx.y==0 materializes o-weights)
// ---------------------------------------------------------------------------
__global__ __launch_bounds__(256) void attn_k(
    const float* __restrict__ QKV, const int* __restrict__ amask,
    const float* __restrict__ cosT, const float* __restrict__ sinT,
    unsigned short* __restrict__ O,
    const int* __restrict__ C2, const float* __restrict__ AM2,
    unsigned short* __restrict__ W2, long cnt8)
{
  __shared__ float ks[SEQ * 132];
  __shared__ float qs[ATILE * 132];
  __shared__ float sc[ATILE * 80];
  __shared__ int am[SEQ];

  if (blockIdx.y == 0) {   // carry: materialize o weights
    float* tb = ks;
    if (threadIdx.x < 16) tb[threadIdx.x] = NF4C[threadIdx.x];
    __syncthreads();
    carry_body(tb, blockIdx.x, gridDim.x, threadIdx.x,
               C2, AM2, W2, D_MODEL, 0, cnt8, 0);
    return;
  }

  int bh = blockIdx.x, it = blockIdx.y - 1;
  int b = bh >> 4, h = bh & (NHEAD - 1);
  const int STR = 3 * D_MODEL;
  const float scale = 0.08838834764831845f;  // 1/sqrt(128)

  const float* Kb = QKV + (size_t)(b * SEQ) * STR + D_MODEL + h * 128;
  for (int idx = threadIdx.x; idx < SEQ * 16; idx += 256) {
    int j = idx >> 4, dq = (idx & 15) << 2;
    float4 a = *(const float4*)(Kb + (size_t)j * STR + dq);
    float4 bb = *(const float4*)(Kb + (size_t)j * STR + dq + 64);
    float4 c4 = *(const float4*)(cosT + j * 64 + dq);
    float4 s4 = *(const float4*)(sinT + j * 64 + dq);
    float* kr = ks + j * 132 + dq;
    kr[0] = a.x*c4.x - bb.x*s4.x; kr[1] = a.y*c4.y - bb.y*s4.y;
    kr[2] = a.z*c4.z - bb.z*s4.z; kr[3] = a.w*c4.w - bb.w*s4.w;
    kr[64] = bb.x*c4.x + a.x*s4.x; kr[65] = bb.y*c4.y + a.y*s4.y;
    kr[66] = bb.z*c4.z + a.z*s4.z; kr[67] = bb.w*c4.w + a.w*s4.w;
  }
  const float* Qb = QKV + (size_t)(b * SEQ) * STR + h * 128;
  for (int idx = threadIdx.x; idx < ATILE * 16; idx += 256) {
    int il = idx >> 4, dq = (idx & 15) << 2;
    int i = it * ATILE + il;
    if (i < SEQ) {
      float4 a = *(const float4*)(Qb + (size_t)i * STR + dq);
      float4 bb = *(const float4*)(Qb + (size_t)i * STR + dq + 64);
      float4 c4 = *(const float4*)(cosT + i * 64 + dq);
      float4 s4 = *(const float4*)(sinT + i * 64 + dq);
      float* qr = qs + il * 132 + dq;
      qr[0] = a.x*c4.x - bb.x*s4.x; qr[1] = a.y*c4.y - bb.y*s4.y;
      qr[2] = a.z*c4.z - bb.z*s4.z; qr[3] = a.w*c4.w - bb.w*s4.w;
      qr[64] = bb.x*c4.x + a.x*s4.x; qr[65] = bb.y*c4.y + a.y*s4.y;
      qr[66] = bb.z*c4.z + a.z*s4.z; qr[67] = bb.w*c4.w + a.w*s4.w;
    }
  }
  for (int j = threadIdx.x; j < SEQ; j += 256) am[j] = amask[b * SEQ + j];
  __syncthreads();

  int wave = threadIdx.x >> 6, lane = threadIdx.x & 63;
  #pragma unroll
  for (int r = 0; r < 4; ++r) {
    int il = wave * 4 + r;
    int i = it * ATILE + il;
    if (i < SEQ) {
      const float4* qr = (const float4*)(qs + il * 132);
      int j1 = lane, j2 = lane + 64;
      float v1 = -1e9f, v2 = -1e9f;
      if (j1 <= i && am[j1]) {
        const float4* kr = (const float4*)(ks + j1 * 132);
        float s = 0.f;
        #pragma unroll 8
        for (int d = 0; d < 32; ++d) {
          float4 a = qr[d], c = kr[d];
          s += a.x*c.x + a.y*c.y + a.z*c.z + a.w*c.w;
        }
        v1 = s * scale;
      }
      if (j2 < SEQ && j2 <= i && am[j2]) {
        const float4* kr = (const float4*)(ks + j2 * 132);
        float s = 0.f;
        #pragma unroll 8
        for (int d = 0; d < 32; ++d) {
          float4 a = qr[d], c = kr[d];
          s += a.x*c.x + a.y*c.y + a.z*c.z + a.w*c.w;
        }
        v2 = s * scale;
      }
      float mx = fmaxf(v1, v2);
      #pragma unroll
      for (int off = 32; off; off >>= 1) mx = fmaxf(mx, __shfl_xor(mx, off));
      float e1 = __expf(v1 - mx);
      float e2 = (j2 < SEQ) ? __expf(v2 - mx) : 0.f;
      float sum = e1 + e2;
      #pragma unroll
      for (int off = 32; off; off >>= 1) sum += __shfl_xor(sum, off);
      float inv = 1.0f / sum;
      sc[il * 80 + j1] = e1 * inv;
      if (j2 < SEQ) sc[il * 80 + j2] = e2 * inv;
    }
  }
  __syncthreads();

  const float* Vbase = QKV + (size_t)(b * SEQ) * STR + 2 * D_MODEL + h * 128;
  for (int idx = threadIdx.x; idx < ATILE * 32; idx += 256) {
    int il = idx >> 5, d4 = (idx & 31) << 2;
    int i = it * ATILE + il;
    if (i >= SEQ) continue;
    float4 acc = {0.f, 0.f, 0.f, 0.f};
    const float* sr = sc + il * 80;
    for (int j = 0; j < SEQ; ++j) {
      float pp = sr[j];
      float4 v = *(const float4*)(Vbase + (size_t)j * STR + d4);
      acc.x += pp * v.x; acc.y += pp * v.y; acc.z += pp * v.z; acc.w += pp * v.w;
    }
    unsigned short* op = O + (size_t)(b * SEQ + i) * D_MODEL + h * 128 + d4;
    op[0] = f2b(acc.x); op[1] = f2b(acc.y); op[2] = f2b(acc.z); op[3] = f2b(acc.w);
  }
}

__global__ void embed_gather(const float* __restrict__ E, const int* __restrict__ ids,
                             float* __restrict__ H)
{
  size_t idx = (size_t)blockIdx.x * 256 + threadIdx.x;
  int m = (int)(idx / D_MODEL);
  int n = (int)(idx % D_MODEL);
  H[idx] = E[(size_t)ids[m] * D_MODEL + n];
}

__global__ __launch_bounds__(256) void final_k(
    const float* __restrict__ H, const int* __restrict__ amask,
    const float* __restrict__ W, float* __restrict__ out)
{
  int b = blockIdx.x;
  __shared__ int len;
  if (threadIdx.x == 0) {
    int s = 0;
    for (int j = 0; j < SEQ; ++j) s += amask[b * SEQ + j];
    len = s - 1;
  }
  __syncthreads();
  const float* hr = H + ((size_t)(b * SEQ + len) * D_MODEL);
  float s = 0.f;
  for (int i = threadIdx.x; i < D_MODEL; i += 256) { float v = hr[i]; s += v * v; }
  __shared__ float red[4];
  #pragma unroll
  for (int off = 32; off; off >>= 1) s += __shfl_down(s, off, 64);
  if ((threadIdx.x & 63) == 0) red[threadIdx.x >> 6] = s;
  __syncthreads();
  float tot = red[0] + red[1] + red[2] + red[3];
  float inv = rsqrtf(tot / (float)D_MODEL + 1e-6f);
  for (int i = threadIdx.x; i < D_MODEL; i += 256)
    out[(size_t)b * D_MODEL + i] = hr[i] * inv * W[i];
}

// ---------------------------------------------------------------------------
extern "C" void kernel_launch(void* const* d_in, const int* in_sizes, int n_in,
                              void* d_out, int out_size, void* d_ws, size_t ws_size,
                              hipStream_t stream) {
  const int*   ids     = (const int*)d_in[0];
  const int*   amask   = (const int*)d_in[1];
  const float* embed   = (const float*)d_in[2];
  const float* ln_attn = (const float*)d_in[3];
  const float* ln_mlp  = (const float*)d_in[4];
  const float* ln_fin  = (const float*)d_in[5];
  const int*   qkvC    = (const int*)d_in[6];
  const float* qkvS    = (const float*)d_in[7];
  const float* qkvA    = (const float*)d_in[8];
  const float* qkvB    = (const float*)d_in[9];
  const int*   oC      = (const int*)d_in[10];
  const float* oS      = (const float*)d_in[11];
  const float* oA      = (const float*)d_in[12];
  const float* oB      = (const float*)d_in[13];
  const int*   guC     = (const int*)d_in[14];
  const float* guS     = (const float*)d_in[15];
  const float* guA     = (const float*)d_in[16];
  const float* guB     = (const float*)d_in[17];
  const int*   dnC     = (const int*)d_in[18];
  const float* dnS     = (const float*)d_in[19];
  const float* dnA     = (const float*)d_in[20];
  const float* dnB     = (const float*)d_in[21];
  float* out = (float*)d_out;

  const int M = M_TOK, Mp = M_PAD, D = D_MODEL, F = F_FFN, R = LRANK;
  float* p = (float*)d_ws;
  float* h    = p; p += (size_t)Mp * D;
  float* qkv  = p; p += (size_t)Mp * 3 * D;
  float* t    = p; p += (size_t)Mp * 48;
  float* cosT = p; p += SEQ * 64;
  float* sinT = p; p += SEQ * 64;
  unsigned short* xbf = (unsigned short*)p; p += (size_t)Mp * D / 2;
  unsigned short* gbf = (unsigned short*)p; p += (size_t)Mp * F / 2;
  unsigned short* wQ = (unsigned short*)p; p += (size_t)3 * D * D / 2;
  unsigned short* wO = (unsigned short*)p; p += (size_t)D * D / 2;
  unsigned short* wG = (unsigned short*)p; p += (size_t)2 * F * D / 2;
  unsigned short* wD = (unsigned short*)p; p += (size_t)D * F / 2;

  rope_table<<<(SEQ*64 + 63)/64, 64, 0, stream>>>(cosT, sinT);
  embed_gather<<<(M * D)/256, 256, 0, stream>>>(embed, ids, h);
  mat_w<<<2048, 256, 0, stream>>>(qkvC, qkvS, wQ, D, (long)3*D*D/8, 0);

  const int mb = Mp / 128;
  const int Gqkv = mb * (3*D/128) * 2;    // 960 (splitk 2)
  const int Go   = mb * (D/128) * 4;      // 640 (splitk 4)
  const int Ggu  = mb * (2*F/128);        // 1280
  const int Gdn  = mb * (D/128) * 8;      // 1280 (splitk 8)
  const long guHalf = (long)F * D / 8;    // half of gu weights in 8-elem units

  for (int l = 0; l < NLAYER; ++l) {
    // ---- attention ----
    rmsnorm_k<<<M, 256, 0, stream>>>(h, ln_attn + (size_t)l * D, xbf, D);
    lora1<<<dim3(M/4, 3), 256, 0, stream>>>(xbf, qkvA + (size_t)l*3*R*D, t, D);
    hipMemsetAsync(qkv, 0, (size_t)Mp * 3 * D * sizeof(float), stream);
    // qkv GEMM (splitk2, fused LoRA on slice0) + carry gu-w half A (50% blocks)
    gemm_bf<<<Gqkv * 2, 256, 0, stream>>>(
        xbf, wQ, qkv, mb, 3*D, D, 0, 2,
        t, qkvB + (size_t)l*3*D*R, 11, 48, 0, nullptr,
        guC + (size_t)l*2*F*D, guS + (size_t)l*2*F*(D/64), wG, D,
        0, guHalf, 1, 1, Gqkv);
    // attn (+ carry row y==0: o weights)
    attn_k<<<dim3(BATCH*NHEAD, (SEQ + ATILE - 1)/ATILE + 1), 256, 0, stream>>>(
        qkv, amask, cosT, sinT, xbf,
        oC + (size_t)l*D*D, oS + (size_t)l*D*(D/64), wO, (long)D*D/8);
    // o GEMM (splitk4) + carry gu-w half B (50% blocks)
    gemm_bf<<<Go * 2, 256, 0, stream>>>(
        xbf, wO, h, mb, D, D, 1, 4, nullptr, nullptr, 0, 0, 0, nullptr,
        guC + (size_t)l*2*F*D, guS + (size_t)l*2*F*(D/64), wG, D,
        guHalf, guHalf, 1, 1, Go);
    lora1<<<dim3(M/4, 1), 256, 0, stream>>>(xbf, oA + (size_t)l*R*D, t, D);
    lora2<<<dim3(D/256, M/8), 256, 0, stream>>>(h, t, oB + (size_t)l*D*R, D, 11, 16);

    // ---- MLP ----
    rmsnorm_k<<<M, 256, 0, stream>>>(h, ln_mlp + (size_t)l * D, xbf, D);
    lora1<<<dim3(M/4, 2), 256, 0, stream>>>(xbf, guA + (size_t)l*2*R*D, t, D);
    // gu GEMM (GUMODE) + carry down-w (25% blocks)
    {
      int q = (Ggu + 2) / 3, G = 4 * q;
      gemm_bf<<<G, 256, 0, stream>>>(
          xbf, wG, nullptr, mb, 2*F, D, 0, 1,
          t, guB + (size_t)l*2*F*R, 0, 32, 1, gbf,
          dnC + (size_t)l*D*F, dnS + (size_t)l*D*(F/64), wD, F,
          0, (long)D*F/8, 0, 3, Ggu);
    }
    // down GEMM (splitk8) + carry next-layer qkv-w (25% blocks)
    if (l + 1 < NLAYER) {
      int q = (Gdn + 2) / 3, G = 4 * q;
      gemm_bf<<<G, 256, 0, stream>>>(
          gbf, wD, h, mb, D, F, 1, 8, nullptr, nullptr, 0, 0, 0, nullptr,
          qkvC + (size_t)(l+1)*3*D*D, qkvS + (size_t)(l+1)*3*D*(D/64), wQ, D,
          0, (long)3*D*D/8, 0, 3, Gdn);
    } else {
      gemm_bf<<<Gdn, 256, 0, stream>>>(
          gbf, wD, h, mb, D, F, 1, 8, nullptr, nullptr, 0, 0, 0, nullptr,
          nullptr, nullptr, nullptr, D, 0, 0, 0, 0, Gdn);
    }
    lora1<<<dim3(M/4, 1), 256, 0, stream>>>(gbf, dnA + (size_t)l*R*F, t, F);
    lora2<<<dim3(D/256, M/8), 256, 0, stream>>>(h, t, dnB + (size_t)l*D*R, D, 11, 16);
  }
  final_k<<<BATCH, 256, 0, stream>>>(h, amask, ln_fin, out);
}

// Round 14
// 1323.287 us; speedup vs baseline: 1.1331x; 1.1331x over previous
//
#include <hip/hip_runtime.h>
#include <cstdint>
#include <cstddef>

#define M_TOK   1232      // B*S
#define M_PAD   1280
#define D_MODEL 2048
#define F_FFN   8192
#define SEQ     77
#define BATCH   16
#define NHEAD   16
#define LRANK   16
#define NLAYER  2
#define ATILE   16
#define MWB     512       // carry (mat_w) blocks appended to GEMM grids

typedef short bf16x8 __attribute__((ext_vector_type(8)));
typedef float f32x4  __attribute__((ext_vector_type(4)));

__device__ __constant__ float NF4C[16] = {
  -1.0f, -0.6961928009986877f, -0.5250730514526367f, -0.39491748809814453f,
  -0.28444138169288635f, -0.18477343022823334f, -0.09105003625154495f, 0.0f,
  0.07958029955625534f, 0.16093020141124725f, 0.24611230194568634f,
  0.33791524171829224f, 0.44070982933044434f, 0.5626170039176941f,
  0.723855197429657f, 1.0f };

__device__ inline unsigned short f2b(float f) {
  unsigned u = __builtin_bit_cast(unsigned, f);
  u += 0x7FFFu + ((u >> 16) & 1u);   // RNE
  return (unsigned short)(u >> 16);
}
__device__ inline float b2f(unsigned short s) {
  return __builtin_bit_cast(float, ((unsigned)s) << 16);
}

// ---------------------------------------------------------------------------
// Standalone weight materialization (prologue only).
// W[rd][k] = bf16(NF4[C[src][k]] * AM[src][k/64]); ilv: rd -> (rd&1)*F + rd>>1
// ---------------------------------------------------------------------------
__global__ __launch_bounds__(256) void mat_w(
    const int* __restrict__ C, const float* __restrict__ AM,
    unsigned short* __restrict__ W, int K, long total8, int ilv)
{
  __shared__ float tb[16];
  if (threadIdx.x < 16) tb[threadIdx.x] = NF4C[threadIdx.x];
  __syncthreads();
  const int KB = K >> 6;
  for (long i = (long)blockIdx.x * 256 + threadIdx.x; i < total8;
       i += (long)gridDim.x * 256) {
    long e = i << 3;
    int rd = (int)(e / K), k = (int)(e - (long)rd * K);
    int srcn = ilv ? ((rd & 1) * F_FFN + (rd >> 1)) : rd;
    float am = AM[(size_t)srcn * KB + (k >> 6)];
    const int4* cp = (const int4*)(C + (size_t)srcn * K + k);
    int4 a = cp[0], b = cp[1];
    uint4 o;
    o.x = (unsigned)f2b(tb[a.x] * am) | ((unsigned)f2b(tb[a.y] * am) << 16);
    o.y = (unsigned)f2b(tb[a.z] * am) | ((unsigned)f2b(tb[a.w] * am) << 16);
    o.z = (unsigned)f2b(tb[b.x] * am) | ((unsigned)f2b(tb[b.y] * am) << 16);
    o.w = (unsigned)f2b(tb[b.z] * am) | ((unsigned)f2b(tb[b.w] * am) << 16);
    *(uint4*)(W + e) = o;
  }
}

// ---------------------------------------------------------------------------
// bf16 GEMM (m97 single-buffer 32KB structure) + APPENDED carry blocks:
// blocks with bid >= Ggemm run the NEXT weight's dequant-materialization
// (grid-stride). When Ggemm+MWB <= resident slot count the carry overlaps
// from t=0; otherwise it fills the retire tail (R12/R13 lesson: never steal
// resident slots from the GEMM). Epilogues: +=/split-K atomics (fused LoRA
// on slice 0)/GUMODE(silu(g)*u->bf16).
// ---------------------------------------------------------------------------
__global__ __launch_bounds__(256, 2) void gemm_bf(
    const unsigned short* __restrict__ X, const unsigned short* __restrict__ W,
    float* __restrict__ O, int mb, int N, int K, int acc_mode, int splitk,
    const float* __restrict__ T, const float* __restrict__ Bm, int sh, int nr,
    int gum, unsigned short* __restrict__ GB,
    const int* __restrict__ C2, const float* __restrict__ AM2,
    unsigned short* __restrict__ W2, int K2, long total8_2, int ilv2, int Ggemm)
{
  __shared__ __align__(16) unsigned short xs[128 * 64];
  __shared__ __align__(16) unsigned short ws[128 * 64];

  int tid = threadIdx.x;

  // ---- carry path: materialize next weight matrix ----
  if ((int)blockIdx.x >= Ggemm) {
    if (total8_2 > 0) {
      float* tb = (float*)xs;
      if (tid < 16) tb[tid] = NF4C[tid];
      __syncthreads();
      int nblk2 = gridDim.x - Ggemm;
      const int KB2 = K2 >> 6;
      for (long i = (long)((int)blockIdx.x - Ggemm) * 256 + tid; i < total8_2;
           i += (long)nblk2 * 256) {
        long e = i << 3;
        int rd = (int)(e / K2), k = (int)(e - (long)rd * K2);
        int srcn = ilv2 ? ((rd & 1) * F_FFN + (rd >> 1)) : rd;
        float am = AM2[(size_t)srcn * KB2 + (k >> 6)];
        const int4* cp = (const int4*)(C2 + (size_t)srcn * K2 + k);
        int4 a = cp[0], b = cp[1];
        uint4 o;
        o.x = (unsigned)f2b(tb[a.x] * am) | ((unsigned)f2b(tb[a.y] * am) << 16);
        o.y = (unsigned)f2b(tb[a.z] * am) | ((unsigned)f2b(tb[a.w] * am) << 16);
        o.z = (unsigned)f2b(tb[b.x] * am) | ((unsigned)f2b(tb[b.y] * am) << 16);
        o.w = (unsigned)f2b(tb[b.z] * am) | ((unsigned)f2b(tb[b.w] * am) << 16);
        *(uint4*)(W2 + e) = o;
      }
    }
    return;
  }

  // XCD-chunked bijective swizzle over the GEMM sub-grid
  int nwg = Ggemm;
  int q8 = nwg >> 3, r8 = nwg & 7;
  int xcd = blockIdx.x & 7, pos = blockIdx.x >> 3;
  int wgid = (xcd < r8) ? (xcd * (q8 + 1) + pos)
                        : (r8 * (q8 + 1) + (xcd - r8) * q8 + pos);
  int nb = N >> 7;
  int per = mb * nb;
  int slice = wgid / per; int rem = wgid - slice * per;
  int nblk = rem / mb, mblk = rem - nblk * mb;
  int row0 = mblk << 7, col0 = nblk << 7;
  int KBtot = K >> 6, kcnt = KBtot / splitk, kbeg = slice * kcnt;

  int wave = tid >> 6, lane = tid & 63;
  int fr = lane & 15, fg = lane >> 4, s7 = fr & 7;
  int wm = (wave >> 1) * 64, wn = (wave & 1) * 64;
  int xg = lane >> 3;
  int xcol = (((lane & 7) ^ (xg & 7)) << 3);

  const unsigned short* Xbase = X + (size_t)row0 * K + (size_t)kbeg * 64;
  const unsigned short* Wbase = W + (size_t)col0 * K + (size_t)kbeg * 64;

  f32x4 accm[4][4];
  #pragma unroll
  for (int i = 0; i < 4; ++i)
    #pragma unroll
    for (int j = 0; j < 4; ++j) accm[i][j] = (f32x4){0.f, 0.f, 0.f, 0.f};

  auto stage = [&](int t) {
    const unsigned short* xb = Xbase + (size_t)t * 64;
    const unsigned short* wb = Wbase + (size_t)t * 64;
    #pragma unroll
    for (int p2 = 0; p2 < 4; ++p2) {
      int c = wave * 4 + p2;
      const unsigned short* gp = xb + (size_t)(c * 8 + xg) * K + xcol;
      __builtin_amdgcn_global_load_lds(
          (const __attribute__((address_space(1))) unsigned int*)gp,
          (__attribute__((address_space(3))) unsigned int*)(xs + c * 512),
          16, 0, 0);
    }
    #pragma unroll
    for (int p2 = 0; p2 < 4; ++p2) {
      int c = wave * 4 + p2;
      const unsigned short* gp = wb + (size_t)(c * 8 + xg) * K + xcol;
      __builtin_amdgcn_global_load_lds(
          (const __attribute__((address_space(1))) unsigned int*)gp,
          (__attribute__((address_space(3))) unsigned int*)(ws + c * 512),
          16, 0, 0);
    }
  };
  auto compute = [&]() {
    bf16x8 b0[4], b1[4];
    #pragma unroll
    for (int ni = 0; ni < 4; ++ni) {
      const unsigned short* wr = ws + (wn + ni * 16 + fr) * 64;
      b0[ni] = *(const bf16x8*)(wr + ((fg ^ s7) << 3));
      b1[ni] = *(const bf16x8*)(wr + (((4 | fg) ^ s7) << 3));
    }
    #pragma unroll
    for (int mi = 0; mi < 4; ++mi) {
      const unsigned short* xr = xs + (wm + mi * 16 + fr) * 64;
      bf16x8 a0 = *(const bf16x8*)(xr + ((fg ^ s7) << 3));
      bf16x8 a1 = *(const bf16x8*)(xr + (((4 | fg) ^ s7) << 3));
      #pragma unroll
      for (int ni = 0; ni < 4; ++ni) {
        accm[mi][ni] = __builtin_amdgcn_mfma_f32_16x16x32_bf16(
            a0, b0[ni], accm[mi][ni], 0, 0, 0);
        accm[mi][ni] = __builtin_amdgcn_mfma_f32_16x16x32_bf16(
            a1, b1[ni], accm[mi][ni], 0, 0, 0);
      }
    }
  };

  stage(0);
  for (int t = 0; t < kcnt; ++t) {
    __syncthreads();
    compute();
    if (t + 1 < kcnt) {
      __syncthreads();
      stage(t + 1);
    }
  }

  if (gum) {
    // ---- GUMODE epilogue: cols interleaved gate/up; out = silu(g)*u ----
    float* Tt = (float*)&xs[0];   // 128 x 32
    float* Bt = (float*)&ws[0];   // 128 x 16 (interleaved rows)
    __syncthreads();
    for (int idx = tid; idx < 128 * 32; idx += 256) {
      int rr = idx >> 5, c = idx & 31;
      int gm = row0 + rr;
      Tt[idx] = (gm < M_TOK) ? T[(size_t)gm * 32 + c] : 0.f;
    }
    for (int idx = tid; idx < 128 * 16; idx += 256) {
      int rr = idx >> 4, c = idx & 15;
      int type = rr & 1, nrow = (col0 + rr) >> 1;
      Bt[idx] = Bm[((size_t)type * F_FFN + nrow) * LRANK + c];
    }
    __syncthreads();
    #pragma unroll
    for (int mi = 0; mi < 4; ++mi)
      #pragma unroll
      for (int ni = 0; ni < 4; ++ni) {
        int gm0 = row0 + wm + mi * 16 + fg * 4;
        int gnl = wn + ni * 16 + fr;
        #pragma unroll
        for (int r = 0; r < 4; ++r) {
          int gm = gm0 + r;
          float vv = accm[mi][ni][r];
          const float* tr = Tt + (wm + mi * 16 + fg * 4 + r) * 32 + ((gnl & 1) << 4);
          const float* br = Bt + gnl * 16;
          float s = 0.f;
          #pragma unroll
          for (int c = 0; c < 16; ++c) s += tr[c] * br[c];
          vv += 2.0f * s;
          float prt = __shfl_xor(vv, 1);
          if (gm < M_TOK && !(fr & 1)) {
            float sig = 1.0f / (1.0f + expf(-vv));
            GB[(size_t)gm * F_FFN + ((col0 + gnl) >> 1)] = f2b(vv * sig * prt);
          }
        }
      }
    return;
  }

  // fused LoRA-2 staging (slice 0 only when split-K)
  int doT = (T != nullptr) && (slice == 0);
  float* Tt = (float*)&xs[0];
  float* Bt = (float*)&ws[0];
  if (doT) {
    __syncthreads();
    int toff = (col0 >> sh) << 4;
    for (int idx = tid; idx < 128 * 16; idx += 256) {
      int rr = idx >> 4, c = idx & 15;
      int gm = row0 + rr;
      Tt[idx] = (gm < M_TOK) ? T[(size_t)gm * nr + toff + c] : 0.f;
      Bt[idx] = Bm[(size_t)(col0 + rr) * LRANK + c];
    }
    __syncthreads();
  }

  #pragma unroll
  for (int mi = 0; mi < 4; ++mi)
    #pragma unroll
    for (int ni = 0; ni < 4; ++ni) {
      int gm0 = row0 + wm + mi * 16 + fg * 4;
      int gnl = wn + ni * 16 + fr;
      int gn = col0 + gnl;
      #pragma unroll
      for (int r = 0; r < 4; ++r) {
        int gm = gm0 + r;
        if (gm < M_TOK) {
          size_t idx = (size_t)gm * N + gn;
          float vv = accm[mi][ni][r];
          if (doT) {
            const float* tr = Tt + (wm + mi * 16 + fg * 4 + r) * 16;
            const float* br = Bt + gnl * 16;
            float s = 0.f;
            #pragma unroll
            for (int c = 0; c < 16; ++c) s += tr[c] * br[c];
            vv += 2.0f * s;
          }
          if (splitk > 1)       atomicAdd(&O[idx], vv);
          else if (acc_mode)    O[idx] += vv;
          else                  O[idx] = vv;
        }
      }
    }
}

// ---------------------------------------------------------------------------
// LoRA stage 1, 4 m-rows per block
__global__ __launch_bounds__(256) void lora1(
    const unsigned short* __restrict__ X, const float* __restrict__ A,
    float* __restrict__ T, int K)
{
  int m0 = blockIdx.x * 4, bi = blockIdx.y, nmat = gridDim.y;
  int g = threadIdx.x >> 4, l16 = threadIdx.x & 15;
  const float* ar = A + (size_t)bi * LRANK * K + (size_t)g * K;
  const unsigned short* x0 = X + (size_t)m0 * K;
  float s0 = 0.f, s1 = 0.f, s2 = 0.f, s3 = 0.f;
  for (int kk = l16 * 4; kk < K; kk += 64) {
    float4 av = *(const float4*)(ar + kk);
    ushort4 v0 = *(const ushort4*)(x0 + kk);
    ushort4 v1 = *(const ushort4*)(x0 + K + kk);
    ushort4 v2 = *(const ushort4*)(x0 + 2 * K + kk);
    ushort4 v3 = *(const ushort4*)(x0 + 3 * K + kk);
    s0 += b2f(v0.x)*av.x + b2f(v0.y)*av.y + b2f(v0.z)*av.z + b2f(v0.w)*av.w;
    s1 += b2f(v1.x)*av.x + b2f(v1.y)*av.y + b2f(v1.z)*av.z + b2f(v1.w)*av.w;
    s2 += b2f(v2.x)*av.x + b2f(v2.y)*av.y + b2f(v2.z)*av.z + b2f(v2.w)*av.w;
    s3 += b2f(v3.x)*av.x + b2f(v3.y)*av.y + b2f(v3.z)*av.z + b2f(v3.w)*av.w;
  }
  #pragma unroll
  for (int off = 8; off; off >>= 1) {
    s0 += __shfl_down(s0, off, 16);
    s1 += __shfl_down(s1, off, 16);
    s2 += __shfl_down(s2, off, 16);
    s3 += __shfl_down(s3, off, 16);
  }
  if (l16 == 0) {
    size_t base = ((size_t)m0 * nmat + bi) * LRANK + g;
    size_t rs = (size_t)nmat * LRANK;
    T[base] = s0; T[base + rs] = s1; T[base + 2*rs] = s2; T[base + 3*rs] = s3;
  }
}

// LoRA stage 2 (for split-K GEMMs), 8 m-rows per block
__global__ __launch_bounds__(256) void lora2(
    float* __restrict__ O, const float* __restrict__ T,
    const float* __restrict__ Bm, int N, int sh, int nr)
{
  int m0 = blockIdx.y * 8;
  int n = blockIdx.x * 256 + threadIdx.x;
  __shared__ float ts[8 * 48];
  for (int i = threadIdx.x; i < 8 * nr; i += 256)
    ts[(i / nr) * 48 + (i % nr)] = T[(size_t)(m0 + i / nr) * nr + (i % nr)];
  __syncthreads();
  const float4* br = (const float4*)(Bm + (size_t)n * LRANK);
  float4 b0 = br[0], b1 = br[1], b2 = br[2], b3 = br[3];
  int toff = ((n >> sh) << 4);
  #pragma unroll
  for (int mi = 0; mi < 8; ++mi) {
    const float* tsb = ts + mi * 48 + toff;
    float s = b0.x*tsb[0] + b0.y*tsb[1] + b0.z*tsb[2] + b0.w*tsb[3]
            + b1.x*tsb[4] + b1.y*tsb[5] + b1.z*tsb[6] + b1.w*tsb[7]
            + b2.x*tsb[8] + b2.y*tsb[9] + b2.z*tsb[10] + b2.w*tsb[11]
            + b3.x*tsb[12] + b3.y*tsb[13] + b3.z*tsb[14] + b3.w*tsb[15];
    O[(size_t)(m0 + mi) * N + n] += 2.0f * s;
  }
}

// ---------------------------------------------------------------------------
__global__ __launch_bounds__(256) void rmsnorm_k(
    const float* __restrict__ H, const float* __restrict__ W,
    unsigned short* __restrict__ X, int D)
{
  int m = blockIdx.x;
  const float* hr = H + (size_t)m * D;
  float s = 0.f;
  for (int i = threadIdx.x; i < D; i += 256) { float v = hr[i]; s += v * v; }
  __shared__ float red[4];
  #pragma unroll
  for (int off = 32; off; off >>= 1) s += __shfl_down(s, off, 64);
  if ((threadIdx.x & 63) == 0) red[threadIdx.x >> 6] = s;
  __syncthreads();
  float tot = red[0] + red[1] + red[2] + red[3];
  float inv = rsqrtf(tot / (float)D + 1e-6f);
  for (int i = threadIdx.x; i < D; i += 256)
    X[(size_t)m * D + i] = f2b(hr[i] * inv * W[i]);
}

__global__ void rope_table(float* __restrict__ cosT, float* __restrict__ sinT)
{
  int idx = blockIdx.x * 64 + threadIdx.x;
  if (idx >= SEQ * 64) return;
  int s = idx >> 6, j = idx & 63;
  float inv = powf(10000.0f, -(float)(2 * j) / 128.0f);
  float f = (float)s * inv;
  cosT[idx] = cosf(f);
  sinT[idx] = sinf(f);
}

// ---------------------------------------------------------------------------
// Attention with fused RoPE: grid (B*H, 5 row-tiles of 16). Roped K and
// roped Q tile staged in LDS (pad 132), wave-parallel softmax, PV from L2.
// ---------------------------------------------------------------------------
__global__ __launch_bounds__(256) void attn_k(
    const float* __restrict__ QKV, const int* __restrict__ amask,
    const float* __restrict__ cosT, const float* __restrict__ sinT,
    unsigned short* __restrict__ O)
{
  int bh = blockIdx.x, it = blockIdx.y;
  int b = bh >> 4, h = bh & (NHEAD - 1);
  const int STR = 3 * D_MODEL;
  __shared__ float ks[SEQ * 132];
  __shared__ float qs[ATILE * 132];
  __shared__ float sc[ATILE * 80];
  __shared__ int am[SEQ];
  const float scale = 0.08838834764831845f;  // 1/sqrt(128)

  const float* Kb = QKV + (size_t)(b * SEQ) * STR + D_MODEL + h * 128;
  for (int idx = threadIdx.x; idx < SEQ * 16; idx += 256) {
    int j = idx >> 4, dq = (idx & 15) << 2;
    float4 a = *(const float4*)(Kb + (size_t)j * STR + dq);
    float4 bb = *(const float4*)(Kb + (size_t)j * STR + dq + 64);
    float4 c4 = *(const float4*)(cosT + j * 64 + dq);
    float4 s4 = *(const float4*)(sinT + j * 64 + dq);
    float* kr = ks + j * 132 + dq;
    kr[0] = a.x*c4.x - bb.x*s4.x; kr[1] = a.y*c4.y - bb.y*s4.y;
    kr[2] = a.z*c4.z - bb.z*s4.z; kr[3] = a.w*c4.w - bb.w*s4.w;
    kr[64] = bb.x*c4.x + a.x*s4.x; kr[65] = bb.y*c4.y + a.y*s4.y;
    kr[66] = bb.z*c4.z + a.z*s4.z; kr[67] = bb.w*c4.w + a.w*s4.w;
  }
  const float* Qb = QKV + (size_t)(b * SEQ) * STR + h * 128;
  for (int idx = threadIdx.x; idx < ATILE * 16; idx += 256) {
    int il = idx >> 4, dq = (idx & 15) << 2;
    int i = it * ATILE + il;
    if (i < SEQ) {
      float4 a = *(const float4*)(Qb + (size_t)i * STR + dq);
      float4 bb = *(const float4*)(Qb + (size_t)i * STR + dq + 64);
      float4 c4 = *(const float4*)(cosT + i * 64 + dq);
      float4 s4 = *(const float4*)(sinT + i * 64 + dq);
      float* qr = qs + il * 132 + dq;
      qr[0] = a.x*c4.x - bb.x*s4.x; qr[1] = a.y*c4.y - bb.y*s4.y;
      qr[2] = a.z*c4.z - bb.z*s4.z; qr[3] = a.w*c4.w - bb.w*s4.w;
      qr[64] = bb.x*c4.x + a.x*s4.x; qr[65] = bb.y*c4.y + a.y*s4.y;
      qr[66] = bb.z*c4.z + a.z*s4.z; qr[67] = bb.w*c4.w + a.w*s4.w;
    }
  }
  for (int j = threadIdx.x; j < SEQ; j += 256) am[j] = amask[b * SEQ + j];
  __syncthreads();

  int wave = threadIdx.x >> 6, lane = threadIdx.x & 63;
  #pragma unroll
  for (int r = 0; r < 4; ++r) {
    int il = wave * 4 + r;
    int i = it * ATILE + il;
    if (i < SEQ) {
      const float4* qr = (const float4*)(qs + il * 132);
      int j1 = lane, j2 = lane + 64;
      float v1 = -1e9f, v2 = -1e9f;
      if (j1 <= i && am[j1]) {
        const float4* kr = (const float4*)(ks + j1 * 132);
        float s = 0.f;
        #pragma unroll 8
        for (int d = 0; d < 32; ++d) {
          float4 a = qr[d], c = kr[d];
          s += a.x*c.x + a.y*c.y + a.z*c.z + a.w*c.w;
        }
        v1 = s * scale;
      }
      if (j2 < SEQ && j2 <= i && am[j2]) {
        const float4* kr = (const float4*)(ks + j2 * 132);
        float s = 0.f;
        #pragma unroll 8
        for (int d = 0; d < 32; ++d) {
          float4 a = qr[d], c = kr[d];
          s += a.x*c.x + a.y*c.y + a.z*c.z + a.w*c.w;
        }
        v2 = s * scale;
      }
      float mx = fmaxf(v1, v2);
      #pragma unroll
      for (int off = 32; off; off >>= 1) mx = fmaxf(mx, __shfl_xor(mx, off));
      float e1 = __expf(v1 - mx);
      float e2 = (j2 < SEQ) ? __expf(v2 - mx) : 0.f;
      float sum = e1 + e2;
      #pragma unroll
      for (int off = 32; off; off >>= 1) sum += __shfl_xor(sum, off);
      float inv = 1.0f / sum;
      sc[il * 80 + j1] = e1 * inv;
      if (j2 < SEQ) sc[il * 80 + j2] = e2 * inv;
    }
  }
  __syncthreads();

  const float* Vbase = QKV + (size_t)(b * SEQ) * STR + 2 * D_MODEL + h * 128;
  for (int idx = threadIdx.x; idx < ATILE * 32; idx += 256) {
    int il = idx >> 5, d4 = (idx & 31) << 2;
    int i = it * ATILE + il;
    if (i >= SEQ) continue;
    float4 acc = {0.f, 0.f, 0.f, 0.f};
    const float* sr = sc + il * 80;
    for (int j = 0; j < SEQ; ++j) {
      float pp = sr[j];
      float4 v = *(const float4*)(Vbase + (size_t)j * STR + d4);
      acc.x += pp * v.x; acc.y += pp * v.y; acc.z += pp * v.z; acc.w += pp * v.w;
    }
    unsigned short* op = O + (size_t)(b * SEQ + i) * D_MODEL + h * 128 + d4;
    op[0] = f2b(acc.x); op[1] = f2b(acc.y); op[2] = f2b(acc.z); op[3] = f2b(acc.w);
  }
}

__global__ void embed_gather(const float* __restrict__ E, const int* __restrict__ ids,
                             float* __restrict__ H)
{
  size_t idx = (size_t)blockIdx.x * 256 + threadIdx.x;
  int m = (int)(idx / D_MODEL);
  int n = (int)(idx % D_MODEL);
  H[idx] = E[(size_t)ids[m] * D_MODEL + n];
}

__global__ __launch_bounds__(256) void final_k(
    const float* __restrict__ H, const int* __restrict__ amask,
    const float* __restrict__ W, float* __restrict__ out)
{
  int b = blockIdx.x;
  __shared__ int len;
  if (threadIdx.x == 0) {
    int s = 0;
    for (int j = 0; j < SEQ; ++j) s += amask[b * SEQ + j];
    len = s - 1;
  }
  __syncthreads();
  const float* hr = H + ((size_t)(b * SEQ + len) * D_MODEL);
  float s = 0.f;
  for (int i = threadIdx.x; i < D_MODEL; i += 256) { float v = hr[i]; s += v * v; }
  __shared__ float red[4];
  #pragma unroll
  for (int off = 32; off; off >>= 1) s += __shfl_down(s, off, 64);
  if ((threadIdx.x & 63) == 0) red[threadIdx.x >> 6] = s;
  __syncthreads();
  float tot = red[0] + red[1] + red[2] + red[3];
  float inv = rsqrtf(tot / (float)D_MODEL + 1e-6f);
  for (int i = threadIdx.x; i < D_MODEL; i += 256)
    out[(size_t)b * D_MODEL + i] = hr[i] * inv * W[i];
}

// ---------------------------------------------------------------------------
extern "C" void kernel_launch(void* const* d_in, const int* in_sizes, int n_in,
                              void* d_out, int out_size, void* d_ws, size_t ws_size,
                              hipStream_t stream) {
  const int*   ids     = (const int*)d_in[0];
  const int*   amask   = (const int*)d_in[1];
  const float* embed   = (const float*)d_in[2];
  const float* ln_attn = (const float*)d_in[3];
  const float* ln_mlp  = (const float*)d_in[4];
  const float* ln_fin  = (const float*)d_in[5];
  const int*   qkvC    = (const int*)d_in[6];
  const float* qkvS    = (const float*)d_in[7];
  const float* qkvA    = (const float*)d_in[8];
  const float* qkvB    = (const float*)d_in[9];
  const int*   oC      = (const int*)d_in[10];
  const float* oS      = (const float*)d_in[11];
  const float* oA      = (const float*)d_in[12];
  const float* oB      = (const float*)d_in[13];
  const int*   guC     = (const int*)d_in[14];
  const float* guS     = (const float*)d_in[15];
  const float* guA     = (const float*)d_in[16];
  const float* guB     = (const float*)d_in[17];
  const int*   dnC     = (const int*)d_in[18];
  const float* dnS     = (const float*)d_in[19];
  const float* dnA     = (const float*)d_in[20];
  const float* dnB     = (const float*)d_in[21];
  float* out = (float*)d_out;

  const int M = M_TOK, Mp = M_PAD, D = D_MODEL, F = F_FFN, R = LRANK;
  float* p = (float*)d_ws;
  float* h    = p; p += (size_t)Mp * D;
  float* qkv  = p; p += (size_t)Mp * 3 * D;
  float* t    = p; p += (size_t)Mp * 48;
  float* cosT = p; p += SEQ * 64;
  float* sinT = p; p += SEQ * 64;
  unsigned short* xbf = (unsigned short*)p; p += (size_t)Mp * D / 2;
  unsigned short* gbf = (unsigned short*)p; p += (size_t)Mp * F / 2;
  unsigned short* wQ = (unsigned short*)p; p += (size_t)3 * D * D / 2;
  unsigned short* wO = (unsigned short*)p; p += (size_t)D * D / 2;
  unsigned short* wG = (unsigned short*)p; p += (size_t)2 * F * D / 2;
  unsigned short* wD = (unsigned short*)p; p += (size_t)D * F / 2;

  rope_table<<<(SEQ*64 + 63)/64, 64, 0, stream>>>(cosT, sinT);
  embed_gather<<<(M * D)/256, 256, 0, stream>>>(embed, ids, h);
  mat_w<<<2048, 256, 0, stream>>>(qkvC, qkvS, wQ, D, (long)3*D*D/8, 0);

  const int mb = Mp / 128;
  const int Gqkv = mb * (3*D/128) * 2;    // 960 (splitk 2)
  const int Go   = mb * (D/128) * 4;      // 640 (splitk 4)
  const int Ggu  = mb * (2*F/128);        // 1280
  const int Gdn  = mb * (D/128) * 8;      // 1280 (splitk 8)

  for (int l = 0; l < NLAYER; ++l) {
    // ---- attention ----
    rmsnorm_k<<<M, 256, 0, stream>>>(h, ln_attn + (size_t)l * D, xbf, D);
    lora1<<<dim3(M/4, 3), 256, 0, stream>>>(xbf, qkvA + (size_t)l*3*R*D, t, D);
    hipMemsetAsync(qkv, 0, (size_t)Mp * 3 * D * sizeof(float), stream);
    // qkv GEMM (splitk2, fused LoRA on slice0) carrying mat_w(o)
    gemm_bf<<<Gqkv + MWB, 256, 0, stream>>>(
        xbf, wQ, qkv, mb, 3*D, D, 0, 2,
        t, qkvB + (size_t)l*3*D*R, 11, 48, 0, nullptr,
        oC + (size_t)l*D*D, oS + (size_t)l*D*(D/64), wO, D, (long)D*D/8, 0, Gqkv);
    attn_k<<<dim3(BATCH*NHEAD, (SEQ + ATILE - 1)/ATILE), 256, 0, stream>>>(
        qkv, amask, cosT, sinT, xbf);
    // o GEMM (split-K 4) carrying mat_w(gu, interleaved)
    gemm_bf<<<Go + MWB, 256, 0, stream>>>(
        xbf, wO, h, mb, D, D, 1, 4, nullptr, nullptr, 0, 0, 0, nullptr,
        guC + (size_t)l*2*F*D, guS + (size_t)l*2*F*(D/64), wG, D, (long)2*F*D/8, 1, Go);
    lora1<<<dim3(M/4, 1), 256, 0, stream>>>(xbf, oA + (size_t)l*R*D, t, D);
    lora2<<<dim3(D/256, M/8), 256, 0, stream>>>(h, t, oB + (size_t)l*D*R, D, 11, 16);

    // ---- MLP ----
    rmsnorm_k<<<M, 256, 0, stream>>>(h, ln_mlp + (size_t)l * D, xbf, D);
    lora1<<<dim3(M/4, 2), 256, 0, stream>>>(xbf, guA + (size_t)l*2*R*D, t, D);
    // gu GEMM (GUMODE) carrying mat_w(down)
    gemm_bf<<<Ggu + MWB, 256, 0, stream>>>(
        xbf, wG, nullptr, mb, 2*F, D, 0, 1,
        t, guB + (size_t)l*2*F*R, 0, 32, 1, gbf,
        dnC + (size_t)l*D*F, dnS + (size_t)l*D*(F/64), wD, F, (long)D*F/8, 0, Ggu);
    // down GEMM (split-K 8) carrying mat_w(qkv, next layer)
    if (l + 1 < NLAYER) {
      gemm_bf<<<Gdn + MWB, 256, 0, stream>>>(
          gbf, wD, h, mb, D, F, 1, 8, nullptr, nullptr, 0, 0, 0, nullptr,
          qkvC + (size_t)(l+1)*3*D*D, qkvS + (size_t)(l+1)*3*D*(D/64),
          wQ, D, (long)3*D*D/8, 0, Gdn);
    } else {
      gemm_bf<<<Gdn, 256, 0, stream>>>(
          gbf, wD, h, mb, D, F, 1, 8, nullptr, nullptr, 0, 0, 0, nullptr,
          nullptr, nullptr, nullptr, D, 0, 0, Gdn);
    }
    lora1<<<dim3(M/4, 1), 256, 0, stream>>>(gbf, dnA + (size_t)l*R*F, t, F);
    lora2<<<dim3(D/256, M/8), 256, 0, stream>>>(h, t, dnB + (size_t)l*D*R, D, 11, 16);
  }
  final_k<<<BATCH, 256, 0, stream>>>(h, amask, ln_fin, out);
}

// Round 15
// 1158.352 us; speedup vs baseline: 1.2945x; 1.1424x over previous
//
#include <hip/hip_runtime.h>
#include <cstdint>
#include <cstddef>

#define M_TOK   1232      // B*S
#define M_PAD   1280
#define D_MODEL 2048
#define F_FFN   8192
#define SEQ     77
#define BATCH   16
#define NHEAD   16
#define LRANK   16
#define NLAYER  2
#define ATILE   16
#define MWB     512       // carry (mat_w) blocks appended to GEMM grids

typedef short bf16x8 __attribute__((ext_vector_type(8)));
typedef float f32x4  __attribute__((ext_vector_type(4)));

__device__ __constant__ float NF4C[16] = {
  -1.0f, -0.6961928009986877f, -0.5250730514526367f, -0.39491748809814453f,
  -0.28444138169288635f, -0.18477343022823334f, -0.09105003625154495f, 0.0f,
  0.07958029955625534f, 0.16093020141124725f, 0.24611230194568634f,
  0.33791524171829224f, 0.44070982933044434f, 0.5626170039176941f,
  0.723855197429657f, 1.0f };

__device__ inline unsigned short f2b(float f) {
  unsigned u = __builtin_bit_cast(unsigned, f);
  u += 0x7FFFu + ((u >> 16) & 1u);   // RNE
  return (unsigned short)(u >> 16);
}
__device__ inline float b2f(unsigned short s) {
  return __builtin_bit_cast(float, ((unsigned)s) << 16);
}

// ---------------------------------------------------------------------------
// Standalone weight materialization (prologue only).
// W[rd][k] = bf16(NF4[C[src][k]] * AM[src][k/64]); ilv: rd -> (rd&1)*F + rd>>1
// ---------------------------------------------------------------------------
__global__ __launch_bounds__(256) void mat_w(
    const int* __restrict__ C, const float* __restrict__ AM,
    unsigned short* __restrict__ W, int K, long total8, int ilv)
{
  __shared__ float tb[16];
  if (threadIdx.x < 16) tb[threadIdx.x] = NF4C[threadIdx.x];
  __syncthreads();
  const int KB = K >> 6;
  for (long i = (long)blockIdx.x * 256 + threadIdx.x; i < total8;
       i += (long)gridDim.x * 256) {
    long e = i << 3;
    int rd = (int)(e / K), k = (int)(e - (long)rd * K);
    int srcn = ilv ? ((rd & 1) * F_FFN + (rd >> 1)) : rd;
    float am = AM[(size_t)srcn * KB + (k >> 6)];
    const int4* cp = (const int4*)(C + (size_t)srcn * K + k);
    int4 a = cp[0], b = cp[1];
    uint4 o;
    o.x = (unsigned)f2b(tb[a.x] * am) | ((unsigned)f2b(tb[a.y] * am) << 16);
    o.y = (unsigned)f2b(tb[a.z] * am) | ((unsigned)f2b(tb[a.w] * am) << 16);
    o.z = (unsigned)f2b(tb[b.x] * am) | ((unsigned)f2b(tb[b.y] * am) << 16);
    o.w = (unsigned)f2b(tb[b.z] * am) | ((unsigned)f2b(tb[b.w] * am) << 16);
    *(uint4*)(W + e) = o;
  }
}

// ---------------------------------------------------------------------------
// bf16 GEMM (m97 single-buffer 32KB structure) + APPENDED carry blocks:
// blocks with bid >= Ggemm run the NEXT weight's dequant-materialization
// (grid-stride). Overlap comes from SPARE block slots (1280 total at 32KB
// LDS) — never steal resident slots from the GEMM (R13 lesson).
// Epilogues: +=/split-K atomics (fused LoRA-2 on slice 0)/GUMODE.
// ---------------------------------------------------------------------------
__global__ __launch_bounds__(256, 2) void gemm_bf(
    const unsigned short* __restrict__ X, const unsigned short* __restrict__ W,
    float* __restrict__ O, int mb, int N, int K, int acc_mode, int splitk,
    const float* __restrict__ T, const float* __restrict__ Bm, int sh, int nr,
    int gum, unsigned short* __restrict__ GB,
    const int* __restrict__ C2, const float* __restrict__ AM2,
    unsigned short* __restrict__ W2, int K2, long total8_2, int ilv2, int Ggemm)
{
  __shared__ __align__(16) unsigned short xs[128 * 64];
  __shared__ __align__(16) unsigned short ws[128 * 64];

  int tid = threadIdx.x;

  // ---- carry path: materialize next weight matrix ----
  if ((int)blockIdx.x >= Ggemm) {
    if (total8_2 > 0) {
      float* tb = (float*)xs;
      if (tid < 16) tb[tid] = NF4C[tid];
      __syncthreads();
      int nblk2 = gridDim.x - Ggemm;
      const int KB2 = K2 >> 6;
      for (long i = (long)((int)blockIdx.x - Ggemm) * 256 + tid; i < total8_2;
           i += (long)nblk2 * 256) {
        long e = i << 3;
        int rd = (int)(e / K2), k = (int)(e - (long)rd * K2);
        int srcn = ilv2 ? ((rd & 1) * F_FFN + (rd >> 1)) : rd;
        float am = AM2[(size_t)srcn * KB2 + (k >> 6)];
        const int4* cp = (const int4*)(C2 + (size_t)srcn * K2 + k);
        int4 a = cp[0], b = cp[1];
        uint4 o;
        o.x = (unsigned)f2b(tb[a.x] * am) | ((unsigned)f2b(tb[a.y] * am) << 16);
        o.y = (unsigned)f2b(tb[a.z] * am) | ((unsigned)f2b(tb[a.w] * am) << 16);
        o.z = (unsigned)f2b(tb[b.x] * am) | ((unsigned)f2b(tb[b.y] * am) << 16);
        o.w = (unsigned)f2b(tb[b.z] * am) | ((unsigned)f2b(tb[b.w] * am) << 16);
        *(uint4*)(W2 + e) = o;
      }
    }
    return;
  }

  // XCD-chunked bijective swizzle over the GEMM sub-grid
  int nwg = Ggemm;
  int q8 = nwg >> 3, r8 = nwg & 7;
  int xcd = blockIdx.x & 7, pos = blockIdx.x >> 3;
  int wgid = (xcd < r8) ? (xcd * (q8 + 1) + pos)
                        : (r8 * (q8 + 1) + (xcd - r8) * q8 + pos);
  int nb = N >> 7;
  int per = mb * nb;
  int slice = wgid / per; int rem = wgid - slice * per;
  int nblk = rem / mb, mblk = rem - nblk * mb;
  int row0 = mblk << 7, col0 = nblk << 7;
  int KBtot = K >> 6, kcnt = KBtot / splitk, kbeg = slice * kcnt;

  int wave = tid >> 6, lane = tid & 63;
  int fr = lane & 15, fg = lane >> 4, s7 = fr & 7;
  int wm = (wave >> 1) * 64, wn = (wave & 1) * 64;
  int xg = lane >> 3;
  int xcol = (((lane & 7) ^ (xg & 7)) << 3);

  const unsigned short* Xbase = X + (size_t)row0 * K + (size_t)kbeg * 64;
  const unsigned short* Wbase = W + (size_t)col0 * K + (size_t)kbeg * 64;

  f32x4 accm[4][4];
  #pragma unroll
  for (int i = 0; i < 4; ++i)
    #pragma unroll
    for (int j = 0; j < 4; ++j) accm[i][j] = (f32x4){0.f, 0.f, 0.f, 0.f};

  auto stage = [&](int t) {
    const unsigned short* xb = Xbase + (size_t)t * 64;
    const unsigned short* wb = Wbase + (size_t)t * 64;
    #pragma unroll
    for (int p2 = 0; p2 < 4; ++p2) {
      int c = wave * 4 + p2;
      const unsigned short* gp = xb + (size_t)(c * 8 + xg) * K + xcol;
      __builtin_amdgcn_global_load_lds(
          (const __attribute__((address_space(1))) unsigned int*)gp,
          (__attribute__((address_space(3))) unsigned int*)(xs + c * 512),
          16, 0, 0);
    }
    #pragma unroll
    for (int p2 = 0; p2 < 4; ++p2) {
      int c = wave * 4 + p2;
      const unsigned short* gp = wb + (size_t)(c * 8 + xg) * K + xcol;
      __builtin_amdgcn_global_load_lds(
          (const __attribute__((address_space(1))) unsigned int*)gp,
          (__attribute__((address_space(3))) unsigned int*)(ws + c * 512),
          16, 0, 0);
    }
  };
  auto compute = [&]() {
    bf16x8 b0[4], b1[4];
    #pragma unroll
    for (int ni = 0; ni < 4; ++ni) {
      const unsigned short* wr = ws + (wn + ni * 16 + fr) * 64;
      b0[ni] = *(const bf16x8*)(wr + ((fg ^ s7) << 3));
      b1[ni] = *(const bf16x8*)(wr + (((4 | fg) ^ s7) << 3));
    }
    #pragma unroll
    for (int mi = 0; mi < 4; ++mi) {
      const unsigned short* xr = xs + (wm + mi * 16 + fr) * 64;
      bf16x8 a0 = *(const bf16x8*)(xr + ((fg ^ s7) << 3));
      bf16x8 a1 = *(const bf16x8*)(xr + (((4 | fg) ^ s7) << 3));
      #pragma unroll
      for (int ni = 0; ni < 4; ++ni) {
        accm[mi][ni] = __builtin_amdgcn_mfma_f32_16x16x32_bf16(
            a0, b0[ni], accm[mi][ni], 0, 0, 0);
        accm[mi][ni] = __builtin_amdgcn_mfma_f32_16x16x32_bf16(
            a1, b1[ni], accm[mi][ni], 0, 0, 0);
      }
    }
  };

  stage(0);
  for (int t = 0; t < kcnt; ++t) {
    __syncthreads();
    compute();
    if (t + 1 < kcnt) {
      __syncthreads();
      stage(t + 1);
    }
  }

  if (gum) {
    // ---- GUMODE epilogue: cols interleaved gate/up; out = silu(g)*u ----
    float* Tt = (float*)&xs[0];   // 128 x 32
    float* Bt = (float*)&ws[0];   // 128 x 16 (interleaved rows)
    __syncthreads();
    for (int idx = tid; idx < 128 * 32; idx += 256) {
      int rr = idx >> 5, c = idx & 31;
      int gm = row0 + rr;
      Tt[idx] = (gm < M_TOK) ? T[(size_t)gm * 32 + c] : 0.f;
    }
    for (int idx = tid; idx < 128 * 16; idx += 256) {
      int rr = idx >> 4, c = idx & 15;
      int type = rr & 1, nrow = (col0 + rr) >> 1;
      Bt[idx] = Bm[((size_t)type * F_FFN + nrow) * LRANK + c];
    }
    __syncthreads();
    #pragma unroll
    for (int mi = 0; mi < 4; ++mi)
      #pragma unroll
      for (int ni = 0; ni < 4; ++ni) {
        int gm0 = row0 + wm + mi * 16 + fg * 4;
        int gnl = wn + ni * 16 + fr;
        #pragma unroll
        for (int r = 0; r < 4; ++r) {
          int gm = gm0 + r;
          float vv = accm[mi][ni][r];
          const float* tr = Tt + (wm + mi * 16 + fg * 4 + r) * 32 + ((gnl & 1) << 4);
          const float* br = Bt + gnl * 16;
          float s = 0.f;
          #pragma unroll
          for (int c = 0; c < 16; ++c) s += tr[c] * br[c];
          vv += 2.0f * s;
          float prt = __shfl_xor(vv, 1);
          if (gm < M_TOK && !(fr & 1)) {
            float sig = 1.0f / (1.0f + expf(-vv));
            GB[(size_t)gm * F_FFN + ((col0 + gnl) >> 1)] = f2b(vv * sig * prt);
          }
        }
      }
    return;
  }

  // fused LoRA-2 staging (slice 0 only when split-K)
  int doT = (T != nullptr) && (slice == 0);
  float* Tt = (float*)&xs[0];
  float* Bt = (float*)&ws[0];
  if (doT) {
    __syncthreads();
    int toff = (col0 >> sh) << 4;
    for (int idx = tid; idx < 128 * 16; idx += 256) {
      int rr = idx >> 4, c = idx & 15;
      int gm = row0 + rr;
      Tt[idx] = (gm < M_TOK) ? T[(size_t)gm * nr + toff + c] : 0.f;
      Bt[idx] = Bm[(size_t)(col0 + rr) * LRANK + c];
    }
    __syncthreads();
  }

  #pragma unroll
  for (int mi = 0; mi < 4; ++mi)
    #pragma unroll
    for (int ni = 0; ni < 4; ++ni) {
      int gm0 = row0 + wm + mi * 16 + fg * 4;
      int gnl = wn + ni * 16 + fr;
      int gn = col0 + gnl;
      #pragma unroll
      for (int r = 0; r < 4; ++r) {
        int gm = gm0 + r;
        if (gm < M_TOK) {
          size_t idx = (size_t)gm * N + gn;
          float vv = accm[mi][ni][r];
          if (doT) {
            const float* tr = Tt + (wm + mi * 16 + fg * 4 + r) * 16;
            const float* br = Bt + gnl * 16;
            float s = 0.f;
            #pragma unroll
            for (int c = 0; c < 16; ++c) s += tr[c] * br[c];
            vv += 2.0f * s;
          }
          if (splitk > 1)       atomicAdd(&O[idx], vv);
          else if (acc_mode)    O[idx] += vv;
          else                  O[idx] = vv;
        }
      }
    }
}

// ---------------------------------------------------------------------------
// LoRA stage 1, 4 m-rows per block
__global__ __launch_bounds__(256) void lora1(
    const unsigned short* __restrict__ X, const float* __restrict__ A,
    float* __restrict__ T, int K)
{
  int m0 = blockIdx.x * 4, bi = blockIdx.y, nmat = gridDim.y;
  int g = threadIdx.x >> 4, l16 = threadIdx.x & 15;
  const float* ar = A + (size_t)bi * LRANK * K + (size_t)g * K;
  const unsigned short* x0 = X + (size_t)m0 * K;
  float s0 = 0.f, s1 = 0.f, s2 = 0.f, s3 = 0.f;
  for (int kk = l16 * 4; kk < K; kk += 64) {
    float4 av = *(const float4*)(ar + kk);
    ushort4 v0 = *(const ushort4*)(x0 + kk);
    ushort4 v1 = *(const ushort4*)(x0 + K + kk);
    ushort4 v2 = *(const ushort4*)(x0 + 2 * K + kk);
    ushort4 v3 = *(const ushort4*)(x0 + 3 * K + kk);
    s0 += b2f(v0.x)*av.x + b2f(v0.y)*av.y + b2f(v0.z)*av.z + b2f(v0.w)*av.w;
    s1 += b2f(v1.x)*av.x + b2f(v1.y)*av.y + b2f(v1.z)*av.z + b2f(v1.w)*av.w;
    s2 += b2f(v2.x)*av.x + b2f(v2.y)*av.y + b2f(v2.z)*av.z + b2f(v2.w)*av.w;
    s3 += b2f(v3.x)*av.x + b2f(v3.y)*av.y + b2f(v3.z)*av.z + b2f(v3.w)*av.w;
  }
  #pragma unroll
  for (int off = 8; off; off >>= 1) {
    s0 += __shfl_down(s0, off, 16);
    s1 += __shfl_down(s1, off, 16);
    s2 += __shfl_down(s2, off, 16);
    s3 += __shfl_down(s3, off, 16);
  }
  if (l16 == 0) {
    size_t base = ((size_t)m0 * nmat + bi) * LRANK + g;
    size_t rs = (size_t)nmat * LRANK;
    T[base] = s0; T[base + rs] = s1; T[base + 2*rs] = s2; T[base + 3*rs] = s3;
  }
}

// ---------------------------------------------------------------------------
__global__ __launch_bounds__(256) void rmsnorm_k(
    const float* __restrict__ H, const float* __restrict__ W,
    unsigned short* __restrict__ X, int D)
{
  int m = blockIdx.x;
  const float* hr = H + (size_t)m * D;
  float s = 0.f;
  for (int i = threadIdx.x; i < D; i += 256) { float v = hr[i]; s += v * v; }
  __shared__ float red[4];
  #pragma unroll
  for (int off = 32; off; off >>= 1) s += __shfl_down(s, off, 64);
  if ((threadIdx.x & 63) == 0) red[threadIdx.x >> 6] = s;
  __syncthreads();
  float tot = red[0] + red[1] + red[2] + red[3];
  float inv = rsqrtf(tot / (float)D + 1e-6f);
  for (int i = threadIdx.x; i < D; i += 256)
    X[(size_t)m * D + i] = f2b(hr[i] * inv * W[i]);
}

__global__ void rope_table(float* __restrict__ cosT, float* __restrict__ sinT)
{
  int idx = blockIdx.x * 64 + threadIdx.x;
  if (idx >= SEQ * 64) return;
  int s = idx >> 6, j = idx & 63;
  float inv = powf(10000.0f, -(float)(2 * j) / 128.0f);
  float f = (float)s * inv;
  cosT[idx] = cosf(f);
  sinT[idx] = sinf(f);
}

// ---------------------------------------------------------------------------
// Attention with fused RoPE: grid (B*H, 5 row-tiles of 16). Roped K and
// roped Q tile staged in LDS (pad 132), wave-parallel softmax, PV from L2.
// ---------------------------------------------------------------------------
__global__ __launch_bounds__(256) void attn_k(
    const float* __restrict__ QKV, const int* __restrict__ amask,
    const float* __restrict__ cosT, const float* __restrict__ sinT,
    unsigned short* __restrict__ O)
{
  int bh = blockIdx.x, it = blockIdx.y;
  int b = bh >> 4, h = bh & (NHEAD - 1);
  const int STR = 3 * D_MODEL;
  __shared__ float ks[SEQ * 132];
  __shared__ float qs[ATILE * 132];
  __shared__ float sc[ATILE * 80];
  __shared__ int am[SEQ];
  const float scale = 0.08838834764831845f;  // 1/sqrt(128)

  const float* Kb = QKV + (size_t)(b * SEQ) * STR + D_MODEL + h * 128;
  for (int idx = threadIdx.x; idx < SEQ * 16; idx += 256) {
    int j = idx >> 4, dq = (idx & 15) << 2;
    float4 a = *(const float4*)(Kb + (size_t)j * STR + dq);
    float4 bb = *(const float4*)(Kb + (size_t)j * STR + dq + 64);
    float4 c4 = *(const float4*)(cosT + j * 64 + dq);
    float4 s4 = *(const float4*)(sinT + j * 64 + dq);
    float* kr = ks + j * 132 + dq;
    kr[0] = a.x*c4.x - bb.x*s4.x; kr[1] = a.y*c4.y - bb.y*s4.y;
    kr[2] = a.z*c4.z - bb.z*s4.z; kr[3] = a.w*c4.w - bb.w*s4.w;
    kr[64] = bb.x*c4.x + a.x*s4.x; kr[65] = bb.y*c4.y + a.y*s4.y;
    kr[66] = bb.z*c4.z + a.z*s4.z; kr[67] = bb.w*c4.w + a.w*s4.w;
  }
  const float* Qb = QKV + (size_t)(b * SEQ) * STR + h * 128;
  for (int idx = threadIdx.x; idx < ATILE * 16; idx += 256) {
    int il = idx >> 4, dq = (idx & 15) << 2;
    int i = it * ATILE + il;
    if (i < SEQ) {
      float4 a = *(const float4*)(Qb + (size_t)i * STR + dq);
      float4 bb = *(const float4*)(Qb + (size_t)i * STR + dq + 64);
      float4 c4 = *(const float4*)(cosT + i * 64 + dq);
      float4 s4 = *(const float4*)(sinT + i * 64 + dq);
      float* qr = qs + il * 132 + dq;
      qr[0] = a.x*c4.x - bb.x*s4.x; qr[1] = a.y*c4.y - bb.y*s4.y;
      qr[2] = a.z*c4.z - bb.z*s4.z; qr[3] = a.w*c4.w - bb.w*s4.w;
      qr[64] = bb.x*c4.x + a.x*s4.x; qr[65] = bb.y*c4.y + a.y*s4.y;
      qr[66] = bb.z*c4.z + a.z*s4.z; qr[67] = bb.w*c4.w + a.w*s4.w;
    }
  }
  for (int j = threadIdx.x; j < SEQ; j += 256) am[j] = amask[b * SEQ + j];
  __syncthreads();

  int wave = threadIdx.x >> 6, lane = threadIdx.x & 63;
  #pragma unroll
  for (int r = 0; r < 4; ++r) {
    int il = wave * 4 + r;
    int i = it * ATILE + il;
    if (i < SEQ) {
      const float4* qr = (const float4*)(qs + il * 132);
      int j1 = lane, j2 = lane + 64;
      float v1 = -1e9f, v2 = -1e9f;
      if (j1 <= i && am[j1]) {
        const float4* kr = (const float4*)(ks + j1 * 132);
        float s = 0.f;
        #pragma unroll 8
        for (int d = 0; d < 32; ++d) {
          float4 a = qr[d], c = kr[d];
          s += a.x*c.x + a.y*c.y + a.z*c.z + a.w*c.w;
        }
        v1 = s * scale;
      }
      if (j2 < SEQ && j2 <= i && am[j2]) {
        const float4* kr = (const float4*)(ks + j2 * 132);
        float s = 0.f;
        #pragma unroll 8
        for (int d = 0; d < 32; ++d) {
          float4 a = qr[d], c = kr[d];
          s += a.x*c.x + a.y*c.y + a.z*c.z + a.w*c.w;
        }
        v2 = s * scale;
      }
      float mx = fmaxf(v1, v2);
      #pragma unroll
      for (int off = 32; off; off >>= 1) mx = fmaxf(mx, __shfl_xor(mx, off));
      float e1 = __expf(v1 - mx);
      float e2 = (j2 < SEQ) ? __expf(v2 - mx) : 0.f;
      float sum = e1 + e2;
      #pragma unroll
      for (int off = 32; off; off >>= 1) sum += __shfl_xor(sum, off);
      float inv = 1.0f / sum;
      sc[il * 80 + j1] = e1 * inv;
      if (j2 < SEQ) sc[il * 80 + j2] = e2 * inv;
    }
  }
  __syncthreads();

  const float* Vbase = QKV + (size_t)(b * SEQ) * STR + 2 * D_MODEL + h * 128;
  for (int idx = threadIdx.x; idx < ATILE * 32; idx += 256) {
    int il = idx >> 5, d4 = (idx & 31) << 2;
    int i = it * ATILE + il;
    if (i >= SEQ) continue;
    float4 acc = {0.f, 0.f, 0.f, 0.f};
    const float* sr = sc + il * 80;
    for (int j = 0; j < SEQ; ++j) {
      float pp = sr[j];
      float4 v = *(const float4*)(Vbase + (size_t)j * STR + d4);
      acc.x += pp * v.x; acc.y += pp * v.y; acc.z += pp * v.z; acc.w += pp * v.w;
    }
    unsigned short* op = O + (size_t)(b * SEQ + i) * D_MODEL + h * 128 + d4;
    op[0] = f2b(acc.x); op[1] = f2b(acc.y); op[2] = f2b(acc.z); op[3] = f2b(acc.w);
  }
}

__global__ void embed_gather(const float* __restrict__ E, const int* __restrict__ ids,
                             float* __restrict__ H)
{
  size_t idx = (size_t)blockIdx.x * 256 + threadIdx.x;
  int m = (int)(idx / D_MODEL);
  int n = (int)(idx % D_MODEL);
  H[idx] = E[(size_t)ids[m] * D_MODEL + n];
}

__global__ __launch_bounds__(256) void final_k(
    const float* __restrict__ H, const int* __restrict__ amask,
    const float* __restrict__ W, float* __restrict__ out)
{
  int b = blockIdx.x;
  __shared__ int len;
  if (threadIdx.x == 0) {
    int s = 0;
    for (int j = 0; j < SEQ; ++j) s += amask[b * SEQ + j];
    len = s - 1;
  }
  __syncthreads();
  const float* hr = H + ((size_t)(b * SEQ + len) * D_MODEL);
  float s = 0.f;
  for (int i = threadIdx.x; i < D_MODEL; i += 256) { float v = hr[i]; s += v * v; }
  __shared__ float red[4];
  #pragma unroll
  for (int off = 32; off; off >>= 1) s += __shfl_down(s, off, 64);
  if ((threadIdx.x & 63) == 0) red[threadIdx.x >> 6] = s;
  __syncthreads();
  float tot = red[0] + red[1] + red[2] + red[3];
  float inv = rsqrtf(tot / (float)D_MODEL + 1e-6f);
  for (int i = threadIdx.x; i < D_MODEL; i += 256)
    out[(size_t)b * D_MODEL + i] = hr[i] * inv * W[i];
}

// ---------------------------------------------------------------------------
extern "C" void kernel_launch(void* const* d_in, const int* in_sizes, int n_in,
                              void* d_out, int out_size, void* d_ws, size_t ws_size,
                              hipStream_t stream) {
  const int*   ids     = (const int*)d_in[0];
  const int*   amask   = (const int*)d_in[1];
  const float* embed   = (const float*)d_in[2];
  const float* ln_attn = (const float*)d_in[3];
  const float* ln_mlp  = (const float*)d_in[4];
  const float* ln_fin  = (const float*)d_in[5];
  const int*   qkvC    = (const int*)d_in[6];
  const float* qkvS    = (const float*)d_in[7];
  const float* qkvA    = (const float*)d_in[8];
  const float* qkvB    = (const float*)d_in[9];
  const int*   oC      = (const int*)d_in[10];
  const float* oS      = (const float*)d_in[11];
  const float* oA      = (const float*)d_in[12];
  const float* oB      = (const float*)d_in[13];
  const int*   guC     = (const int*)d_in[14];
  const float* guS     = (const float*)d_in[15];
  const float* guA     = (const float*)d_in[16];
  const float* guB     = (const float*)d_in[17];
  const int*   dnC     = (const int*)d_in[18];
  const float* dnS     = (const float*)d_in[19];
  const float* dnA     = (const float*)d_in[20];
  const float* dnB     = (const float*)d_in[21];
  float* out = (float*)d_out;

  const int M = M_TOK, Mp = M_PAD, D = D_MODEL, F = F_FFN, R = LRANK;
  float* p = (float*)d_ws;
  float* h    = p; p += (size_t)Mp * D;
  float* qkv  = p; p += (size_t)Mp * 3 * D;
  float* t    = p; p += (size_t)Mp * 48;
  float* cosT = p; p += SEQ * 64;
  float* sinT = p; p += SEQ * 64;
  unsigned short* xbf = (unsigned short*)p; p += (size_t)Mp * D / 2;
  unsigned short* gbf = (unsigned short*)p; p += (size_t)Mp * F / 2;
  unsigned short* wQ = (unsigned short*)p; p += (size_t)3 * D * D / 2;
  unsigned short* wO = (unsigned short*)p; p += (size_t)D * D / 2;
  unsigned short* wG = (unsigned short*)p; p += (size_t)2 * F * D / 2;
  unsigned short* wD = (unsigned short*)p; p += (size_t)D * F / 2;

  rope_table<<<(SEQ*64 + 63)/64, 64, 0, stream>>>(cosT, sinT);
  embed_gather<<<(M * D)/256, 256, 0, stream>>>(embed, ids, h);
  mat_w<<<2048, 256, 0, stream>>>(qkvC, qkvS, wQ, D, (long)3*D*D/8, 0);

  const int mb = Mp / 128;
  const int Gqkv = mb * (3*D/128);        // 480 (splitk 1, fused LoRA)
  const int Go   = mb * (D/128) * 4;      // 640 (splitk 4, fused LoRA slice0)
  const int Ggu  = mb * (2*F/128);        // 1280 (GUMODE)
  const int Gdn  = mb * (D/128) * 4;      // 640 (splitk 4, fused LoRA slice0)

  for (int l = 0; l < NLAYER; ++l) {
    // ---- attention ----
    rmsnorm_k<<<M, 256, 0, stream>>>(h, ln_attn + (size_t)l * D, xbf, D);
    lora1<<<dim3(M/4, 3), 256, 0, stream>>>(xbf, qkvA + (size_t)l*3*R*D, t, D);
    // qkv GEMM (+fused LoRA) carrying mat_w(o)
    gemm_bf<<<Gqkv + MWB, 256, 0, stream>>>(
        xbf, wQ, qkv, mb, 3*D, D, 0, 1,
        t, qkvB + (size_t)l*3*D*R, 11, 48, 0, nullptr,
        oC + (size_t)l*D*D, oS + (size_t)l*D*(D/64), wO, D, (long)D*D/8, 0, Gqkv);
    attn_k<<<dim3(BATCH*NHEAD, (SEQ + ATILE - 1)/ATILE), 256, 0, stream>>>(
        qkv, amask, cosT, sinT, xbf);
    // o LoRA-1 (input = attn output xbf), then o GEMM with fused LoRA-2
    lora1<<<dim3(M/4, 1), 256, 0, stream>>>(xbf, oA + (size_t)l*R*D, t, D);
    // o GEMM (split-K 4, fused LoRA on slice0) carrying mat_w(gu, interleaved)
    gemm_bf<<<Go + MWB, 256, 0, stream>>>(
        xbf, wO, h, mb, D, D, 1, 4,
        t, oB + (size_t)l*D*R, 11, 16, 0, nullptr,
        guC + (size_t)l*2*F*D, guS + (size_t)l*2*F*(D/64), wG, D, (long)2*F*D/8, 1, Go);

    // ---- MLP ----
    rmsnorm_k<<<M, 256, 0, stream>>>(h, ln_mlp + (size_t)l * D, xbf, D);
    lora1<<<dim3(M/4, 2), 256, 0, stream>>>(xbf, guA + (size_t)l*2*R*D, t, D);
    // gu GEMM (GUMODE) carrying mat_w(down)
    gemm_bf<<<Ggu + MWB, 256, 0, stream>>>(
        xbf, wG, nullptr, mb, 2*F, D, 0, 1,
        t, guB + (size_t)l*2*F*R, 0, 32, 1, gbf,
        dnC + (size_t)l*D*F, dnS + (size_t)l*D*(F/64), wD, F, (long)D*F/8, 0, Ggu);
    // down LoRA-1 (input = gbf), then down GEMM with fused LoRA-2
    lora1<<<dim3(M/4, 1), 256, 0, stream>>>(gbf, dnA + (size_t)l*R*F, t, F);
    // down GEMM (split-K 4, fused LoRA on slice0) carrying mat_w(qkv, next layer)
    if (l + 1 < NLAYER) {
      gemm_bf<<<Gdn + MWB, 256, 0, stream>>>(
          gbf, wD, h, mb, D, F, 1, 4,
          t, dnB + (size_t)l*D*R, 11, 16, 0, nullptr,
          qkvC + (size_t)(l+1)*3*D*D, qkvS + (size_t)(l+1)*3*D*(D/64),
          wQ, D, (long)3*D*D/8, 0, Gdn);
    } else {
      gemm_bf<<<Gdn, 256, 0, stream>>>(
          gbf, wD, h, mb, D, F, 1, 4,
          t, dnB + (size_t)l*D*R, 11, 16, 0, nullptr,
          nullptr, nullptr, nullptr, D, 0, 0, Gdn);
    }
  }
  final_k<<<BATCH, 256, 0, stream>>>(h, amask, ln_fin, out);
}

// Round 16
// 1141.970 us; speedup vs baseline: 1.3130x; 1.0143x over previous
//
#include <hip/hip_runtime.h>
#include <cstdint>
#include <cstddef>

#define M_TOK   1232      // B*S
#define M_PAD   1280
#define D_MODEL 2048
#define F_FFN   8192
#define SEQ     77
#define BATCH   16
#define NHEAD   16
#define LRANK   16
#define NLAYER  2
#define ATILE   16

typedef short bf16x8 __attribute__((ext_vector_type(8)));
typedef float f32x4  __attribute__((ext_vector_type(4)));

__device__ __constant__ float NF4C[16] = {
  -1.0f, -0.6961928009986877f, -0.5250730514526367f, -0.39491748809814453f,
  -0.28444138169288635f, -0.18477343022823334f, -0.09105003625154495f, 0.0f,
  0.07958029955625534f, 0.16093020141124725f, 0.24611230194568634f,
  0.33791524171829224f, 0.44070982933044434f, 0.5626170039176941f,
  0.723855197429657f, 1.0f };

__device__ inline unsigned short f2b(float f) {
  unsigned u = __builtin_bit_cast(unsigned, f);
  u += 0x7FFFu + ((u >> 16) & 1u);   // RNE
  return (unsigned short)(u >> 16);
}
__device__ inline float b2f(unsigned short s) {
  return __builtin_bit_cast(float, ((unsigned)s) << 16);
}

// carry body: materialize bf16 weights over [beg8, beg8+cnt8) 8-elem units
__device__ inline void carry_body(const float* tb, long cid, long ncb, int tid,
                                  const int* C2, const float* AM2,
                                  unsigned short* W2, int K2, long beg8,
                                  long cnt8, int ilv2) {
  const int KB2 = K2 >> 6;
  for (long i = cid * 256 + tid; i < cnt8; i += ncb * 256) {
    long e = (beg8 + i) << 3;
    int rd = (int)(e / K2), k = (int)(e - (long)rd * K2);
    int srcn = ilv2 ? ((rd & 1) * F_FFN + (rd >> 1)) : rd;
    float am = AM2[(size_t)srcn * KB2 + (k >> 6)];
    const int4* cp = (const int4*)(C2 + (size_t)srcn * K2 + k);
    int4 a = cp[0], b = cp[1];
    uint4 o;
    o.x = (unsigned)f2b(tb[a.x] * am) | ((unsigned)f2b(tb[a.y] * am) << 16);
    o.y = (unsigned)f2b(tb[a.z] * am) | ((unsigned)f2b(tb[a.w] * am) << 16);
    o.z = (unsigned)f2b(tb[b.x] * am) | ((unsigned)f2b(tb[b.y] * am) << 16);
    o.w = (unsigned)f2b(tb[b.z] * am) | ((unsigned)f2b(tb[b.w] * am) << 16);
    *(uint4*)(W2 + e) = o;
  }
}

// ---------------------------------------------------------------------------
__global__ __launch_bounds__(256) void mat_w(
    const int* __restrict__ C, const float* __restrict__ AM,
    unsigned short* __restrict__ W, int K, long total8, int ilv)
{
  __shared__ float tb[16];
  if (threadIdx.x < 16) tb[threadIdx.x] = NF4C[threadIdx.x];
  __syncthreads();
  carry_body(tb, blockIdx.x, gridDim.x, threadIdx.x, C, AM, W, K, 0, total8, ilv);
}

// ---------------------------------------------------------------------------
// bf16 GEMM (m97 single-buffer 32KB) + TWO appended carry segments:
// bids [Ggemm, Ggemm+nc1) -> weight range 1; [Ggemm+nc1, gridDim) -> range 2.
// Overlap comes from SPARE block slots (1280 at 32KB LDS); carry work is
// balanced to each dispatch's spare-slot-time (R13/R15 lessons).
// Epilogues: +=/split-K atomics (fused LoRA-2 on slice 0)/GUMODE.
// ---------------------------------------------------------------------------
__global__ __launch_bounds__(256, 2) void gemm_bf(
    const unsigned short* __restrict__ X, const unsigned short* __restrict__ W,
    float* __restrict__ O, int mb, int N, int K, int acc_mode, int splitk,
    const float* __restrict__ T, const float* __restrict__ Bm, int sh, int nr,
    int gum, unsigned short* __restrict__ GB,
    const int* __restrict__ C1, const float* __restrict__ AM1,
    unsigned short* __restrict__ W1, int K1, long beg1, long cnt1, int ilv1, int nc1,
    const int* __restrict__ C2, const float* __restrict__ AM2,
    unsigned short* __restrict__ W2, int K2, long beg2, long cnt2, int ilv2,
    int Ggemm)
{
  __shared__ __align__(16) unsigned short xs[128 * 64];
  __shared__ __align__(16) unsigned short ws[128 * 64];

  int tid = threadIdx.x;

  // ---- carry paths ----
  if ((int)blockIdx.x >= Ggemm) {
    int cb = (int)blockIdx.x - Ggemm;
    float* tb = (float*)xs;
    if (tid < 16) tb[tid] = NF4C[tid];
    __syncthreads();
    if (cb < nc1) {
      if (cnt1 > 0)
        carry_body(tb, cb, nc1, tid, C1, AM1, W1, K1, beg1, cnt1, ilv1);
    } else {
      int ncb2 = gridDim.x - Ggemm - nc1;
      if (cnt2 > 0 && ncb2 > 0)
        carry_body(tb, cb - nc1, ncb2, tid, C2, AM2, W2, K2, beg2, cnt2, ilv2);
    }
    return;
  }

  // XCD-chunked bijective swizzle over the GEMM sub-grid
  int nwg = Ggemm;
  int q8 = nwg >> 3, r8 = nwg & 7;
  int xcd = blockIdx.x & 7, pos = blockIdx.x >> 3;
  int wgid = (xcd < r8) ? (xcd * (q8 + 1) + pos)
                        : (r8 * (q8 + 1) + (xcd - r8) * q8 + pos);
  int nb = N >> 7;
  int per = mb * nb;
  int slice = wgid / per; int rem = wgid - slice * per;
  int nblk = rem / mb, mblk = rem - nblk * mb;
  int row0 = mblk << 7, col0 = nblk << 7;
  int KBtot = K >> 6, kcnt = KBtot / splitk, kbeg = slice * kcnt;

  int wave = tid >> 6, lane = tid & 63;
  int fr = lane & 15, fg = lane >> 4, s7 = fr & 7;
  int wm = (wave >> 1) * 64, wn = (wave & 1) * 64;
  int xg = lane >> 3;
  int xcol = (((lane & 7) ^ (xg & 7)) << 3);

  const unsigned short* Xbase = X + (size_t)row0 * K + (size_t)kbeg * 64;
  const unsigned short* Wbase = W + (size_t)col0 * K + (size_t)kbeg * 64;

  f32x4 accm[4][4];
  #pragma unroll
  for (int i = 0; i < 4; ++i)
    #pragma unroll
    for (int j = 0; j < 4; ++j) accm[i][j] = (f32x4){0.f, 0.f, 0.f, 0.f};

  auto stage = [&](int t) {
    const unsigned short* xb = Xbase + (size_t)t * 64;
    const unsigned short* wb = Wbase + (size_t)t * 64;
    #pragma unroll
    for (int p2 = 0; p2 < 4; ++p2) {
      int c = wave * 4 + p2;
      const unsigned short* gp = xb + (size_t)(c * 8 + xg) * K + xcol;
      __builtin_amdgcn_global_load_lds(
          (const __attribute__((address_space(1))) unsigned int*)gp,
          (__attribute__((address_space(3))) unsigned int*)(xs + c * 512),
          16, 0, 0);
    }
    #pragma unroll
    for (int p2 = 0; p2 < 4; ++p2) {
      int c = wave * 4 + p2;
      const unsigned short* gp = wb + (size_t)(c * 8 + xg) * K + xcol;
      __builtin_amdgcn_global_load_lds(
          (const __attribute__((address_space(1))) unsigned int*)gp,
          (__attribute__((address_space(3))) unsigned int*)(ws + c * 512),
          16, 0, 0);
    }
  };
  auto compute = [&]() {
    bf16x8 b0[4], b1[4];
    #pragma unroll
    for (int ni = 0; ni < 4; ++ni) {
      const unsigned short* wr = ws + (wn + ni * 16 + fr) * 64;
      b0[ni] = *(const bf16x8*)(wr + ((fg ^ s7) << 3));
      b1[ni] = *(const bf16x8*)(wr + (((4 | fg) ^ s7) << 3));
    }
    #pragma unroll
    for (int mi = 0; mi < 4; ++mi) {
      const unsigned short* xr = xs + (wm + mi * 16 + fr) * 64;
      bf16x8 a0 = *(const bf16x8*)(xr + ((fg ^ s7) << 3));
      bf16x8 a1 = *(const bf16x8*)(xr + (((4 | fg) ^ s7) << 3));
      #pragma unroll
      for (int ni = 0; ni < 4; ++ni) {
        accm[mi][ni] = __builtin_amdgcn_mfma_f32_16x16x32_bf16(
            a0, b0[ni], accm[mi][ni], 0, 0, 0);
        accm[mi][ni] = __builtin_amdgcn_mfma_f32_16x16x32_bf16(
            a1, b1[ni], accm[mi][ni], 0, 0, 0);
      }
    }
  };

  stage(0);
  for (int t = 0; t < kcnt; ++t) {
    __syncthreads();
    compute();
    if (t + 1 < kcnt) {
      __syncthreads();
      stage(t + 1);
    }
  }

  if (gum) {
    // ---- GUMODE epilogue: cols interleaved gate/up; out = silu(g)*u ----
    float* Tt = (float*)&xs[0];   // 128 x 32
    float* Bt = (float*)&ws[0];   // 128 x 16 (interleaved rows)
    __syncthreads();
    for (int idx = tid; idx < 128 * 32; idx += 256) {
      int rr = idx >> 5, c = idx & 31;
      int gm = row0 + rr;
      Tt[idx] = (gm < M_TOK) ? T[(size_t)gm * 32 + c] : 0.f;
    }
    for (int idx = tid; idx < 128 * 16; idx += 256) {
      int rr = idx >> 4, c = idx & 15;
      int type = rr & 1, nrow = (col0 + rr) >> 1;
      Bt[idx] = Bm[((size_t)type * F_FFN + nrow) * LRANK + c];
    }
    __syncthreads();
    #pragma unroll
    for (int mi = 0; mi < 4; ++mi)
      #pragma unroll
      for (int ni = 0; ni < 4; ++ni) {
        int gm0 = row0 + wm + mi * 16 + fg * 4;
        int gnl = wn + ni * 16 + fr;
        #pragma unroll
        for (int r = 0; r < 4; ++r) {
          int gm = gm0 + r;
          float vv = accm[mi][ni][r];
          const float* tr = Tt + (wm + mi * 16 + fg * 4 + r) * 32 + ((gnl & 1) << 4);
          const float* br = Bt + gnl * 16;
          float s = 0.f;
          #pragma unroll
          for (int c = 0; c < 16; ++c) s += tr[c] * br[c];
          vv += 2.0f * s;
          float prt = __shfl_xor(vv, 1);
          if (gm < M_TOK && !(fr & 1)) {
            float sig = 1.0f / (1.0f + expf(-vv));
            GB[(size_t)gm * F_FFN + ((col0 + gnl) >> 1)] = f2b(vv * sig * prt);
          }
        }
      }
    return;
  }

  // fused LoRA-2 staging (slice 0 only when split-K)
  int doT = (T != nullptr) && (slice == 0);
  float* Tt = (float*)&xs[0];
  float* Bt = (float*)&ws[0];
  if (doT) {
    __syncthreads();
    int toff = (col0 >> sh) << 4;
    for (int idx = tid; idx < 128 * 16; idx += 256) {
      int rr = idx >> 4, c = idx & 15;
      int gm = row0 + rr;
      Tt[idx] = (gm < M_TOK) ? T[(size_t)gm * nr + toff + c] : 0.f;
      Bt[idx] = Bm[(size_t)(col0 + rr) * LRANK + c];
    }
    __syncthreads();
  }

  #pragma unroll
  for (int mi = 0; mi < 4; ++mi)
    #pragma unroll
    for (int ni = 0; ni < 4; ++ni) {
      int gm0 = row0 + wm + mi * 16 + fg * 4;
      int gnl = wn + ni * 16 + fr;
      int gn = col0 + gnl;
      #pragma unroll
      for (int r = 0; r < 4; ++r) {
        int gm = gm0 + r;
        if (gm < M_TOK) {
          size_t idx = (size_t)gm * N + gn;
          float vv = accm[mi][ni][r];
          if (doT) {
            const float* tr = Tt + (wm + mi * 16 + fg * 4 + r) * 16;
            const float* br = Bt + gnl * 16;
            float s = 0.f;
            #pragma unroll
            for (int c = 0; c < 16; ++c) s += tr[c] * br[c];
            vv += 2.0f * s;
          }
          if (splitk > 1)       atomicAdd(&O[idx], vv);
          else if (acc_mode)    O[idx] += vv;
          else                  O[idx] = vv;
        }
      }
    }
}

// ---------------------------------------------------------------------------
__global__ __launch_bounds__(256) void lora1(
    const unsigned short* __restrict__ X, const float* __restrict__ A,
    float* __restrict__ T, int K)
{
  int m0 = blockIdx.x * 4, bi = blockIdx.y, nmat = gridDim.y;
  int g = threadIdx.x >> 4, l16 = threadIdx.x & 15;
  const float* ar = A + (size_t)bi * LRANK * K + (size_t)g * K;
  const unsigned short* x0 = X + (size_t)m0 * K;
  float s0 = 0.f, s1 = 0.f, s2 = 0.f, s3 = 0.f;
  for (int kk = l16 * 4; kk < K; kk += 64) {
    float4 av = *(const float4*)(ar + kk);
    ushort4 v0 = *(const ushort4*)(x0 + kk);
    ushort4 v1 = *(const ushort4*)(x0 + K + kk);
    ushort4 v2 = *(const ushort4*)(x0 + 2 * K + kk);
    ushort4 v3 = *(const ushort4*)(x0 + 3 * K + kk);
    s0 += b2f(v0.x)*av.x + b2f(v0.y)*av.y + b2f(v0.z)*av.z + b2f(v0.w)*av.w;
    s1 += b2f(v1.x)*av.x + b2f(v1.y)*av.y + b2f(v1.z)*av.z + b2f(v1.w)*av.w;
    s2 += b2f(v2.x)*av.x + b2f(v2.y)*av.y + b2f(v2.z)*av.z + b2f(v2.w)*av.w;
    s3 += b2f(v3.x)*av.x + b2f(v3.y)*av.y + b2f(v3.z)*av.z + b2f(v3.w)*av.w;
  }
  #pragma unroll
  for (int off = 8; off; off >>= 1) {
    s0 += __shfl_down(s0, off, 16);
    s1 += __shfl_down(s1, off, 16);
    s2 += __shfl_down(s2, off, 16);
    s3 += __shfl_down(s3, off, 16);
  }
  if (l16 == 0) {
    size_t base = ((size_t)m0 * nmat + bi) * LRANK + g;
    size_t rs = (size_t)nmat * LRANK;
    T[base] = s0; T[base + rs] = s1; T[base + 2*rs] = s2; T[base + 3*rs] = s3;
  }
}

// ---------------------------------------------------------------------------
__global__ __launch_bounds__(256) void rmsnorm_k(
    const float* __restrict__ H, const float* __restrict__ W,
    unsigned short* __restrict__ X, int D)
{
  int m = blockIdx.x;
  const float* hr = H + (size_t)m * D;
  float s = 0.f;
  for (int i = threadIdx.x; i < D; i += 256) { float v = hr[i]; s += v * v; }
  __shared__ float red[4];
  #pragma unroll
  for (int off = 32; off; off >>= 1) s += __shfl_down(s, off, 64);
  if ((threadIdx.x & 63) == 0) red[threadIdx.x >> 6] = s;
  __syncthreads();
  float tot = red[0] + red[1] + red[2] + red[3];
  float inv = rsqrtf(tot / (float)D + 1e-6f);
  for (int i = threadIdx.x; i < D; i += 256)
    X[(size_t)m * D + i] = f2b(hr[i] * inv * W[i]);
}

__global__ void rope_table(float* __restrict__ cosT, float* __restrict__ sinT)
{
  int idx = blockIdx.x * 64 + threadIdx.x;
  if (idx >= SEQ * 64) return;
  int s = idx >> 6, j = idx & 63;
  float inv = powf(10000.0f, -(float)(2 * j) / 128.0f);
  float f = (float)s * inv;
  cosT[idx] = cosf(f);
  sinT[idx] = sinf(f);
}

// ---------------------------------------------------------------------------
__global__ __launch_bounds__(256) void attn_k(
    const float* __restrict__ QKV, const int* __restrict__ amask,
    const float* __restrict__ cosT, const float* __restrict__ sinT,
    unsigned short* __restrict__ O)
{
  int bh = blockIdx.x, it = blockIdx.y;
  int b = bh >> 4, h = bh & (NHEAD - 1);
  const int STR = 3 * D_MODEL;
  __shared__ float ks[SEQ * 132];
  __shared__ float qs[ATILE * 132];
  __shared__ float sc[ATILE * 80];
  __shared__ int am[SEQ];
  const float scale = 0.08838834764831845f;  // 1/sqrt(128)

  const float* Kb = QKV + (size_t)(b * SEQ) * STR + D_MODEL + h * 128;
  for (int idx = threadIdx.x; idx < SEQ * 16; idx += 256) {
    int j = idx >> 4, dq = (idx & 15) << 2;
    float4 a = *(const float4*)(Kb + (size_t)j * STR + dq);
    float4 bb = *(const float4*)(Kb + (size_t)j * STR + dq + 64);
    float4 c4 = *(const float4*)(cosT + j * 64 + dq);
    float4 s4 = *(const float4*)(sinT + j * 64 + dq);
    float* kr = ks + j * 132 + dq;
    kr[0] = a.x*c4.x - bb.x*s4.x; kr[1] = a.y*c4.y - bb.y*s4.y;
    kr[2] = a.z*c4.z - bb.z*s4.z; kr[3] = a.w*c4.w - bb.w*s4.w;
    kr[64] = bb.x*c4.x + a.x*s4.x; kr[65] = bb.y*c4.y + a.y*s4.y;
    kr[66] = bb.z*c4.z + a.z*s4.z; kr[67] = bb.w*c4.w + a.w*s4.w;
  }
  const float* Qb = QKV + (size_t)(b * SEQ) * STR + h * 128;
  for (int idx = threadIdx.x; idx < ATILE * 16; idx += 256) {
    int il = idx >> 4, dq = (idx & 15) << 2;
    int i = it * ATILE + il;
    if (i < SEQ) {
      float4 a = *(const float4*)(Qb + (size_t)i * STR + dq);
      float4 bb = *(const float4*)(Qb + (size_t)i * STR + dq + 64);
      float4 c4 = *(const float4*)(cosT + i * 64 + dq);
      float4 s4 = *(const float4*)(sinT + i * 64 + dq);
      float* qr = qs + il * 132 + dq;
      qr[0] = a.x*c4.x - bb.x*s4.x; qr[1] = a.y*c4.y - bb.y*s4.y;
      qr[2] = a.z*c4.z - bb.z*s4.z; qr[3] = a.w*c4.w - bb.w*s4.w;
      qr[64] = bb.x*c4.x + a.x*s4.x; qr[65] = bb.y*c4.y + a.y*s4.y;
      qr[66] = bb.z*c4.z + a.z*s4.z; qr[67] = bb.w*c4.w + a.w*s4.w;
    }
  }
  for (int j = threadIdx.x; j < SEQ; j += 256) am[j] = amask[b * SEQ + j];
  __syncthreads();

  int wave = threadIdx.x >> 6, lane = threadIdx.x & 63;
  #pragma unroll
  for (int r = 0; r < 4; ++r) {
    int il = wave * 4 + r;
    int i = it * ATILE + il;
    if (i < SEQ) {
      const float4* qr = (const float4*)(qs + il * 132);
      int j1 = lane, j2 = lane + 64;
      float v1 = -1e9f, v2 = -1e9f;
      if (j1 <= i && am[j1]) {
        const float4* kr = (const float4*)(ks + j1 * 132);
        float s = 0.f;
        #pragma unroll 8
        for (int d = 0; d < 32; ++d) {
          float4 a = qr[d], c = kr[d];
          s += a.x*c.x + a.y*c.y + a.z*c.z + a.w*c.w;
        }
        v1 = s * scale;
      }
      if (j2 < SEQ && j2 <= i && am[j2]) {
        const float4* kr = (const float4*)(ks + j2 * 132);
        float s = 0.f;
        #pragma unroll 8
        for (int d = 0; d < 32; ++d) {
          float4 a = qr[d], c = kr[d];
          s += a.x*c.x + a.y*c.y + a.z*c.z + a.w*c.w;
        }
        v2 = s * scale;
      }
      float mx = fmaxf(v1, v2);
      #pragma unroll
      for (int off = 32; off; off >>= 1) mx = fmaxf(mx, __shfl_xor(mx, off));
      float e1 = __expf(v1 - mx);
      float e2 = (j2 < SEQ) ? __expf(v2 - mx) : 0.f;
      float sum = e1 + e2;
      #pragma unroll
      for (int off = 32; off; off >>= 1) sum += __shfl_xor(sum, off);
      float inv = 1.0f / sum;
      sc[il * 80 + j1] = e1 * inv;
      if (j2 < SEQ) sc[il * 80 + j2] = e2 * inv;
    }
  }
  __syncthreads();

  const float* Vbase = QKV + (size_t)(b * SEQ) * STR + 2 * D_MODEL + h * 128;
  for (int idx = threadIdx.x; idx < ATILE * 32; idx += 256) {
    int il = idx >> 5, d4 = (idx & 31) << 2;
    int i = it * ATILE + il;
    if (i >= SEQ) continue;
    float4 acc = {0.f, 0.f, 0.f, 0.f};
    const float* sr = sc + il * 80;
    for (int j = 0; j < SEQ; ++j) {
      float pp = sr[j];
      float4 v = *(const float4*)(Vbase + (size_t)j * STR + d4);
      acc.x += pp * v.x; acc.y += pp * v.y; acc.z += pp * v.z; acc.w += pp * v.w;
    }
    unsigned short* op = O + (size_t)(b * SEQ + i) * D_MODEL + h * 128 + d4;
    op[0] = f2b(acc.x); op[1] = f2b(acc.y); op[2] = f2b(acc.z); op[3] = f2b(acc.w);
  }
}

__global__ void embed_gather(const float* __restrict__ E, const int* __restrict__ ids,
                             float* __restrict__ H)
{
  size_t idx = (size_t)blockIdx.x * 256 + threadIdx.x;
  int m = (int)(idx / D_MODEL);
  int n = (int)(idx % D_MODEL);
  H[idx] = E[(size_t)ids[m] * D_MODEL + n];
}

__global__ __launch_bounds__(256) void final_k(
    const float* __restrict__ H, const int* __restrict__ amask,
    const float* __restrict__ W, float* __restrict__ out)
{
  int b = blockIdx.x;
  __shared__ int len;
  if (threadIdx.x == 0) {
    int s = 0;
    for (int j = 0; j < SEQ; ++j) s += amask[b * SEQ + j];
    len = s - 1;
  }
  __syncthreads();
  const float* hr = H + ((size_t)(b * SEQ + len) * D_MODEL);
  float s = 0.f;
  for (int i = threadIdx.x; i < D_MODEL; i += 256) { float v = hr[i]; s += v * v; }
  __shared__ float red[4];
  #pragma unroll
  for (int off = 32; off; off >>= 1) s += __shfl_down(s, off, 64);
  if ((threadIdx.x & 63) == 0) red[threadIdx.x >> 6] = s;
  __syncthreads();
  float tot = red[0] + red[1] + red[2] + red[3];
  float inv = rsqrtf(tot / (float)D_MODEL + 1e-6f);
  for (int i = threadIdx.x; i < D_MODEL; i += 256)
    out[(size_t)b * D_MODEL + i] = hr[i] * inv * W[i];
}

// ---------------------------------------------------------------------------
extern "C" void kernel_launch(void* const* d_in, const int* in_sizes, int n_in,
                              void* d_out, int out_size, void* d_ws, size_t ws_size,
                              hipStream_t stream) {
  const int*   ids     = (const int*)d_in[0];
  const int*   amask   = (const int*)d_in[1];
  const float* embed   = (const float*)d_in[2];
  const float* ln_attn = (const float*)d_in[3];
  const float* ln_mlp  = (const float*)d_in[4];
  const float* ln_fin  = (const float*)d_in[5];
  const int*   qkvC    = (const int*)d_in[6];
  const float* qkvS    = (const float*)d_in[7];
  const float* qkvA    = (const float*)d_in[8];
  const float* qkvB    = (const float*)d_in[9];
  const int*   oC      = (const int*)d_in[10];
  const float* oS      = (const float*)d_in[11];
  const float* oA      = (const float*)d_in[12];
  const float* oB      = (const float*)d_in[13];
  const int*   guC     = (const int*)d_in[14];
  const float* guS     = (const float*)d_in[15];
  const float* guA     = (const float*)d_in[16];
  const float* guB     = (const float*)d_in[17];
  const int*   dnC     = (const int*)d_in[18];
  const float* dnS     = (const float*)d_in[19];
  const float* dnA     = (const float*)d_in[20];
  const float* dnB     = (const float*)d_in[21];
  float* out = (float*)d_out;

  const int M = M_TOK, Mp = M_PAD, D = D_MODEL, F = F_FFN, R = LRANK;
  float* p = (float*)d_ws;
  float* h    = p; p += (size_t)Mp * D;
  float* qkv  = p; p += (size_t)Mp * 3 * D;
  float* t    = p; p += (size_t)Mp * 48;
  float* cosT = p; p += SEQ * 64;
  float* sinT = p; p += SEQ * 64;
  unsigned short* xbf = (unsigned short*)p; p += (size_t)Mp * D / 2;
  unsigned short* gbf = (unsigned short*)p; p += (size_t)Mp * F / 2;
  unsigned short* wQ = (unsigned short*)p; p += (size_t)3 * D * D / 2;
  unsigned short* wO = (unsigned short*)p; p += (size_t)D * D / 2;
  unsigned short* wG = (unsigned short*)p; p += (size_t)2 * F * D / 2;
  unsigned short* wD = (unsigned short*)p; p += (size_t)D * F / 2;

  rope_table<<<(SEQ*64 + 63)/64, 64, 0, stream>>>(cosT, sinT);
  embed_gather<<<(M * D)/256, 256, 0, stream>>>(embed, ids, h);
  mat_w<<<2048, 256, 0, stream>>>(qkvC, qkvS, wQ, D, (long)3*D*D/8, 0);

  const int mb = Mp / 128;
  const int Gqkv = mb * (3*D/128);        // 480
  const int Go   = mb * (D/128) * 4;      // 640 (splitk 4)
  const int Ggu  = mb * (2*F/128);        // 1280
  const int Gdn  = mb * (D/128) * 4;      // 640 (splitk 4)
  const long oT8   = (long)D * D / 8;
  const long guT8  = (long)2 * F * D / 8;
  const long guA8  = guT8 * 5 / 8;        // qkv-carried share (spare-slot balance)
  const long dnT8  = (long)D * F / 8;
  const long qkvT8 = (long)3 * D * D / 8;

  for (int l = 0; l < NLAYER; ++l) {
    // ---- attention ----
    rmsnorm_k<<<M, 256, 0, stream>>>(h, ln_attn + (size_t)l * D, xbf, D);
    lora1<<<dim3(M/4, 3), 256, 0, stream>>>(xbf, qkvA + (size_t)l*3*R*D, t, D);
    // qkv GEMM (+fused LoRA); carries: seg1 = o-w (192 blks), seg2 = gu-w 5/8 (576)
    gemm_bf<<<Gqkv + 768, 256, 0, stream>>>(
        xbf, wQ, qkv, mb, 3*D, D, 0, 1,
        t, qkvB + (size_t)l*3*D*R, 11, 48, 0, nullptr,
        oC + (size_t)l*D*D, oS + (size_t)l*D*(D/64), wO, D, 0, oT8, 0, 192,
        guC + (size_t)l*2*F*D, guS + (size_t)l*2*F*(D/64), wG, D, 0, guA8, 1, Gqkv);
    attn_k<<<dim3(BATCH*NHEAD, (SEQ + ATILE - 1)/ATILE), 256, 0, stream>>>(
        qkv, amask, cosT, sinT, xbf);
    lora1<<<dim3(M/4, 1), 256, 0, stream>>>(xbf, oA + (size_t)l*R*D, t, D);
    // o GEMM (splitk4, fused LoRA slice0); carries remaining 3/8 of gu-w (512 blks)
    gemm_bf<<<Go + 512, 256, 0, stream>>>(
        xbf, wO, h, mb, D, D, 1, 4,
        t, oB + (size_t)l*D*R, 11, 16, 0, nullptr,
        guC + (size_t)l*2*F*D, guS + (size_t)l*2*F*(D/64), wG, D,
        guA8, guT8 - guA8, 1, 512,
        nullptr, nullptr, nullptr, D, 0, 0, 0, Go);

    // ---- MLP ----
    rmsnorm_k<<<M, 256, 0, stream>>>(h, ln_mlp + (size_t)l * D, xbf, D);
    lora1<<<dim3(M/4, 2), 256, 0, stream>>>(xbf, guA + (size_t)l*2*R*D, t, D);
    // gu GEMM (GUMODE); carries down-w (512 blks, retire-tail)
    gemm_bf<<<Ggu + 512, 256, 0, stream>>>(
        xbf, wG, nullptr, mb, 2*F, D, 0, 1,
        t, guB + (size_t)l*2*F*R, 0, 32, 1, gbf,
        dnC + (size_t)l*D*F, dnS + (size_t)l*D*(F/64), wD, F, 0, dnT8, 0, 512,
        nullptr, nullptr, nullptr, D, 0, 0, 0, Ggu);
    lora1<<<dim3(M/4, 1), 256, 0, stream>>>(gbf, dnA + (size_t)l*R*F, t, F);
    // down GEMM (splitk4, fused LoRA slice0); carries next-layer qkv-w
    if (l + 1 < NLAYER) {
      gemm_bf<<<Gdn + 512, 256, 0, stream>>>(
          gbf, wD, h, mb, D, F, 1, 4,
          t, dnB + (size_t)l*D*R, 11, 16, 0, nullptr,
          qkvC + (size_t)(l+1)*3*D*D, qkvS + (size_t)(l+1)*3*D*(D/64),
          wQ, D, 0, qkvT8, 0, 512,
          nullptr, nullptr, nullptr, D, 0, 0, 0, Gdn);
    } else {
      gemm_bf<<<Gdn, 256, 0, stream>>>(
          gbf, wD, h, mb, D, F, 1, 4,
          t, dnB + (size_t)l*D*R, 11, 16, 0, nullptr,
          nullptr, nullptr, nullptr, D, 0, 0, 0, 0,
          nullptr, nullptr, nullptr, D, 0, 0, 0, Gdn);
    }
  }
  final_k<<<BATCH, 256, 0, stream>>>(h, amask, ln_fin, out);
}

// Round 17
// 1134.665 us; speedup vs baseline: 1.3215x; 1.0064x over previous
//
#include <hip/hip_runtime.h>
#include <cstdint>
#include <cstddef>

#define M_TOK   1232      // B*S
#define M_PAD   1280
#define D_MODEL 2048
#define F_FFN   8192
#define SEQ     77
#define BATCH   16
#define NHEAD   16
#define LRANK   16
#define NLAYER  2
#define ATILE   16
#define NT_ATT  5         // attn row-tiles

typedef short bf16x8 __attribute__((ext_vector_type(8)));
typedef float f32x4  __attribute__((ext_vector_type(4)));

__device__ __constant__ float NF4C[16] = {
  -1.0f, -0.6961928009986877f, -0.5250730514526367f, -0.39491748809814453f,
  -0.28444138169288635f, -0.18477343022823334f, -0.09105003625154495f, 0.0f,
  0.07958029955625534f, 0.16093020141124725f, 0.24611230194568634f,
  0.33791524171829224f, 0.44070982933044434f, 0.5626170039176941f,
  0.723855197429657f, 1.0f };

__device__ inline unsigned short f2b(float f) {
  unsigned u = __builtin_bit_cast(unsigned, f);
  u += 0x7FFFu + ((u >> 16) & 1u);   // RNE
  return (unsigned short)(u >> 16);
}
__device__ inline float b2f(unsigned short s) {
  return __builtin_bit_cast(float, ((unsigned)s) << 16);
}

// carry body: materialize bf16 weights over [beg8, beg8+cnt8) 8-elem units
__device__ inline void carry_body(const float* tb, long cid, long ncb, int tid,
                                  const int* C2, const float* AM2,
                                  unsigned short* W2, int K2, long beg8,
                                  long cnt8, int ilv2) {
  const int KB2 = K2 >> 6;
  for (long i = cid * 256 + tid; i < cnt8; i += ncb * 256) {
    long e = (beg8 + i) << 3;
    int rd = (int)(e / K2), k = (int)(e - (long)rd * K2);
    int srcn = ilv2 ? ((rd & 1) * F_FFN + (rd >> 1)) : rd;
    float am = AM2[(size_t)srcn * KB2 + (k >> 6)];
    const int4* cp = (const int4*)(C2 + (size_t)srcn * K2 + k);
    int4 a = cp[0], b = cp[1];
    uint4 o;
    o.x = (unsigned)f2b(tb[a.x] * am) | ((unsigned)f2b(tb[a.y] * am) << 16);
    o.y = (unsigned)f2b(tb[a.z] * am) | ((unsigned)f2b(tb[a.w] * am) << 16);
    o.z = (unsigned)f2b(tb[b.x] * am) | ((unsigned)f2b(tb[b.y] * am) << 16);
    o.w = (unsigned)f2b(tb[b.z] * am) | ((unsigned)f2b(tb[b.w] * am) << 16);
    *(uint4*)(W2 + e) = o;
  }
}

// ---------------------------------------------------------------------------
__global__ __launch_bounds__(256) void mat_w(
    const int* __restrict__ C, const float* __restrict__ AM,
    unsigned short* __restrict__ W, int K, long total8, int ilv)
{
  __shared__ float tb[16];
  if (threadIdx.x < 16) tb[threadIdx.x] = NF4C[threadIdx.x];
  __syncthreads();
  carry_body(tb, blockIdx.x, gridDim.x, threadIdx.x, C, AM, W, K, 0, total8, ilv);
}

// ---------------------------------------------------------------------------
// bf16 GEMM (m97 single-buffer 32KB) + TWO appended carry segments:
// bids [Ggemm, Ggemm+nc1) -> weight range 1; [Ggemm+nc1, gridDim) -> range 2.
// Overlap comes from SPARE block slots (1280 at 32KB LDS); carry work is
// balanced to each dispatch's spare-slot-time (R13/R15/R16 lessons).
// Epilogues: +=/split-K atomics (fused LoRA-2 on slice 0)/GUMODE.
// ---------------------------------------------------------------------------
__global__ __launch_bounds__(256, 2) void gemm_bf(
    const unsigned short* __restrict__ X, const unsigned short* __restrict__ W,
    float* __restrict__ O, int mb, int N, int K, int acc_mode, int splitk,
    const float* __restrict__ T, const float* __restrict__ Bm, int sh, int nr,
    int gum, unsigned short* __restrict__ GB,
    const int* __restrict__ C1, const float* __restrict__ AM1,
    unsigned short* __restrict__ W1, int K1, long beg1, long cnt1, int ilv1, int nc1,
    const int* __restrict__ C2, const float* __restrict__ AM2,
    unsigned short* __restrict__ W2, int K2, long beg2, long cnt2, int ilv2,
    int Ggemm)
{
  __shared__ __align__(16) unsigned short xs[128 * 64];
  __shared__ __align__(16) unsigned short ws[128 * 64];

  int tid = threadIdx.x;

  // ---- carry paths ----
  if ((int)blockIdx.x >= Ggemm) {
    int cb = (int)blockIdx.x - Ggemm;
    float* tb = (float*)xs;
    if (tid < 16) tb[tid] = NF4C[tid];
    __syncthreads();
    if (cb < nc1) {
      if (cnt1 > 0)
        carry_body(tb, cb, nc1, tid, C1, AM1, W1, K1, beg1, cnt1, ilv1);
    } else {
      int ncb2 = gridDim.x - Ggemm - nc1;
      if (cnt2 > 0 && ncb2 > 0)
        carry_body(tb, cb - nc1, ncb2, tid, C2, AM2, W2, K2, beg2, cnt2, ilv2);
    }
    return;
  }

  // XCD-chunked bijective swizzle over the GEMM sub-grid
  int nwg = Ggemm;
  int q8 = nwg >> 3, r8 = nwg & 7;
  int xcd = blockIdx.x & 7, pos = blockIdx.x >> 3;
  int wgid = (xcd < r8) ? (xcd * (q8 + 1) + pos)
                        : (r8 * (q8 + 1) + (xcd - r8) * q8 + pos);
  int nb = N >> 7;
  int per = mb * nb;
  int slice = wgid / per; int rem = wgid - slice * per;
  int nblk = rem / mb, mblk = rem - nblk * mb;
  int row0 = mblk << 7, col0 = nblk << 7;
  int KBtot = K >> 6, kcnt = KBtot / splitk, kbeg = slice * kcnt;

  int wave = tid >> 6, lane = tid & 63;
  int fr = lane & 15, fg = lane >> 4, s7 = fr & 7;
  int wm = (wave >> 1) * 64, wn = (wave & 1) * 64;
  int xg = lane >> 3;
  int xcol = (((lane & 7) ^ (xg & 7)) << 3);

  const unsigned short* Xbase = X + (size_t)row0 * K + (size_t)kbeg * 64;
  const unsigned short* Wbase = W + (size_t)col0 * K + (size_t)kbeg * 64;

  f32x4 accm[4][4];
  #pragma unroll
  for (int i = 0; i < 4; ++i)
    #pragma unroll
    for (int j = 0; j < 4; ++j) accm[i][j] = (f32x4){0.f, 0.f, 0.f, 0.f};

  auto stage = [&](int t) {
    const unsigned short* xb = Xbase + (size_t)t * 64;
    const unsigned short* wb = Wbase + (size_t)t * 64;
    #pragma unroll
    for (int p2 = 0; p2 < 4; ++p2) {
      int c = wave * 4 + p2;
      const unsigned short* gp = xb + (size_t)(c * 8 + xg) * K + xcol;
      __builtin_amdgcn_global_load_lds(
          (const __attribute__((address_space(1))) unsigned int*)gp,
          (__attribute__((address_space(3))) unsigned int*)(xs + c * 512),
          16, 0, 0);
    }
    #pragma unroll
    for (int p2 = 0; p2 < 4; ++p2) {
      int c = wave * 4 + p2;
      const unsigned short* gp = wb + (size_t)(c * 8 + xg) * K + xcol;
      __builtin_amdgcn_global_load_lds(
          (const __attribute__((address_space(1))) unsigned int*)gp,
          (__attribute__((address_space(3))) unsigned int*)(ws + c * 512),
          16, 0, 0);
    }
  };
  auto compute = [&]() {
    bf16x8 b0[4], b1[4];
    #pragma unroll
    for (int ni = 0; ni < 4; ++ni) {
      const unsigned short* wr = ws + (wn + ni * 16 + fr) * 64;
      b0[ni] = *(const bf16x8*)(wr + ((fg ^ s7) << 3));
      b1[ni] = *(const bf16x8*)(wr + (((4 | fg) ^ s7) << 3));
    }
    #pragma unroll
    for (int mi = 0; mi < 4; ++mi) {
      const unsigned short* xr = xs + (wm + mi * 16 + fr) * 64;
      bf16x8 a0 = *(const bf16x8*)(xr + ((fg ^ s7) << 3));
      bf16x8 a1 = *(const bf16x8*)(xr + (((4 | fg) ^ s7) << 3));
      #pragma unroll
      for (int ni = 0; ni < 4; ++ni) {
        accm[mi][ni] = __builtin_amdgcn_mfma_f32_16x16x32_bf16(
            a0, b0[ni], accm[mi][ni], 0, 0, 0);
        accm[mi][ni] = __builtin_amdgcn_mfma_f32_16x16x32_bf16(
            a1, b1[ni], accm[mi][ni], 0, 0, 0);
      }
    }
  };

  stage(0);
  for (int t = 0; t < kcnt; ++t) {
    __syncthreads();
    compute();
    if (t + 1 < kcnt) {
      __syncthreads();
      stage(t + 1);
    }
  }

  if (gum) {
    // ---- GUMODE epilogue: cols interleaved gate/up; out = silu(g)*u ----
    float* Tt = (float*)&xs[0];   // 128 x 32
    float* Bt = (float*)&ws[0];   // 128 x 16 (interleaved rows)
    __syncthreads();
    for (int idx = tid; idx < 128 * 32; idx += 256) {
      int rr = idx >> 5, c = idx & 31;
      int gm = row0 + rr;
      Tt[idx] = (gm < M_TOK) ? T[(size_t)gm * 32 + c] : 0.f;
    }
    for (int idx = tid; idx < 128 * 16; idx += 256) {
      int rr = idx >> 4, c = idx & 15;
      int type = rr & 1, nrow = (col0 + rr) >> 1;
      Bt[idx] = Bm[((size_t)type * F_FFN + nrow) * LRANK + c];
    }
    __syncthreads();
    #pragma unroll
    for (int mi = 0; mi < 4; ++mi)
      #pragma unroll
      for (int ni = 0; ni < 4; ++ni) {
        int gm0 = row0 + wm + mi * 16 + fg * 4;
        int gnl = wn + ni * 16 + fr;
        #pragma unroll
        for (int r = 0; r < 4; ++r) {
          int gm = gm0 + r;
          float vv = accm[mi][ni][r];
          const float* tr = Tt + (wm + mi * 16 + fg * 4 + r) * 32 + ((gnl & 1) << 4);
          const float* br = Bt + gnl * 16;
          float s = 0.f;
          #pragma unroll
          for (int c = 0; c < 16; ++c) s += tr[c] * br[c];
          vv += 2.0f * s;
          float prt = __shfl_xor(vv, 1);
          if (gm < M_TOK && !(fr & 1)) {
            float sig = 1.0f / (1.0f + expf(-vv));
            GB[(size_t)gm * F_FFN + ((col0 + gnl) >> 1)] = f2b(vv * sig * prt);
          }
        }
      }
    return;
  }

  // fused LoRA-2 staging (slice 0 only when split-K)
  int doT = (T != nullptr) && (slice == 0);
  float* Tt = (float*)&xs[0];
  float* Bt = (float*)&ws[0];
  if (doT) {
    __syncthreads();
    int toff = (col0 >> sh) << 4;
    for (int idx = tid; idx < 128 * 16; idx += 256) {
      int rr = idx >> 4, c = idx & 15;
      int gm = row0 + rr;
      Tt[idx] = (gm < M_TOK) ? T[(size_t)gm * nr + toff + c] : 0.f;
      Bt[idx] = Bm[(size_t)(col0 + rr) * LRANK + c];
    }
    __syncthreads();
  }

  #pragma unroll
  for (int mi = 0; mi < 4; ++mi)
    #pragma unroll
    for (int ni = 0; ni < 4; ++ni) {
      int gm0 = row0 + wm + mi * 16 + fg * 4;
      int gnl = wn + ni * 16 + fr;
      int gn = col0 + gnl;
      #pragma unroll
      for (int r = 0; r < 4; ++r) {
        int gm = gm0 + r;
        if (gm < M_TOK) {
          size_t idx = (size_t)gm * N + gn;
          float vv = accm[mi][ni][r];
          if (doT) {
            const float* tr = Tt + (wm + mi * 16 + fg * 4 + r) * 16;
            const float* br = Bt + gnl * 16;
            float s = 0.f;
            #pragma unroll
            for (int c = 0; c < 16; ++c) s += tr[c] * br[c];
            vv += 2.0f * s;
          }
          if (splitk > 1)       atomicAdd(&O[idx], vv);
          else if (acc_mode)    O[idx] += vv;
          else                  O[idx] = vv;
        }
      }
    }
}

// ---------------------------------------------------------------------------
__global__ __launch_bounds__(256) void lora1(
    const unsigned short* __restrict__ X, const float* __restrict__ A,
    float* __restrict__ T, int K)
{
  int m0 = blockIdx.x * 4, bi = blockIdx.y, nmat = gridDim.y;
  int g = threadIdx.x >> 4, l16 = threadIdx.x & 15;
  const float* ar = A + (size_t)bi * LRANK * K + (size_t)g * K;
  const unsigned short* x0 = X + (size_t)m0 * K;
  float s0 = 0.f, s1 = 0.f, s2 = 0.f, s3 = 0.f;
  for (int kk = l16 * 4; kk < K; kk += 64) {
    float4 av = *(const float4*)(ar + kk);
    ushort4 v0 = *(const ushort4*)(x0 + kk);
    ushort4 v1 = *(const ushort4*)(x0 + K + kk);
    ushort4 v2 = *(const ushort4*)(x0 + 2 * K + kk);
    ushort4 v3 = *(const ushort4*)(x0 + 3 * K + kk);
    s0 += b2f(v0.x)*av.x + b2f(v0.y)*av.y + b2f(v0.z)*av.z + b2f(v0.w)*av.w;
    s1 += b2f(v1.x)*av.x + b2f(v1.y)*av.y + b2f(v1.z)*av.z + b2f(v1.w)*av.w;
    s2 += b2f(v2.x)*av.x + b2f(v2.y)*av.y + b2f(v2.z)*av.z + b2f(v2.w)*av.w;
    s3 += b2f(v3.x)*av.x + b2f(v3.y)*av.y + b2f(v3.z)*av.z + b2f(v3.w)*av.w;
  }
  #pragma unroll
  for (int off = 8; off; off >>= 1) {
    s0 += __shfl_down(s0, off, 16);
    s1 += __shfl_down(s1, off, 16);
    s2 += __shfl_down(s2, off, 16);
    s3 += __shfl_down(s3, off, 16);
  }
  if (l16 == 0) {
    size_t base = ((size_t)m0 * nmat + bi) * LRANK + g;
    size_t rs = (size_t)nmat * LRANK;
    T[base] = s0; T[base + rs] = s1; T[base + 2*rs] = s2; T[base + 3*rs] = s3;
  }
}

// ---------------------------------------------------------------------------
__global__ __launch_bounds__(256) void rmsnorm_k(
    const float* __restrict__ H, const float* __restrict__ W,
    unsigned short* __restrict__ X, int D)
{
  int m = blockIdx.x;
  const float* hr = H + (size_t)m * D;
  float s = 0.f;
  for (int i = threadIdx.x; i < D; i += 256) { float v = hr[i]; s += v * v; }
  __shared__ float red[4];
  #pragma unroll
  for (int off = 32; off; off >>= 1) s += __shfl_down(s, off, 64);
  if ((threadIdx.x & 63) == 0) red[threadIdx.x >> 6] = s;
  __syncthreads();
  float tot = red[0] + red[1] + red[2] + red[3];
  float inv = rsqrtf(tot / (float)D + 1e-6f);
  for (int i = threadIdx.x; i < D; i += 256)
    X[(size_t)m * D + i] = f2b(hr[i] * inv * W[i]);
}

__global__ void rope_table(float* __restrict__ cosT, float* __restrict__ sinT)
{
  int idx = blockIdx.x * 64 + threadIdx.x;
  if (idx >= SEQ * 64) return;
  int s = idx >> 6, j = idx & 63;
  float inv = powf(10000.0f, -(float)(2 * j) / 128.0f);
  float f = (float)s * inv;
  cosT[idx] = cosf(f);
  sinT[idx] = sinf(f);
}

// ---------------------------------------------------------------------------
// Attention with fused RoPE + carry row (blockIdx.y == NT_ATT materializes
// the o-weights while attention runs — attn is L2-bound with slack).
// ---------------------------------------------------------------------------
__global__ __launch_bounds__(256) void attn_k(
    const float* __restrict__ QKV, const int* __restrict__ amask,
    const float* __restrict__ cosT, const float* __restrict__ sinT,
    unsigned short* __restrict__ O,
    const int* __restrict__ C2, const float* __restrict__ AM2,
    unsigned short* __restrict__ W2, long cnt8)
{
  __shared__ float ks[SEQ * 132];
  __shared__ float qs[ATILE * 132];
  __shared__ float sc[ATILE * 80];
  __shared__ int am[SEQ];

  if (blockIdx.y == NT_ATT) {   // carry row: materialize o weights
    float* tb = ks;
    if (threadIdx.x < 16) tb[threadIdx.x] = NF4C[threadIdx.x];
    __syncthreads();
    carry_body(tb, blockIdx.x, gridDim.x, threadIdx.x,
               C2, AM2, W2, D_MODEL, 0, cnt8, 0);
    return;
  }

  int bh = blockIdx.x, it = blockIdx.y;
  int b = bh >> 4, h = bh & (NHEAD - 1);
  const int STR = 3 * D_MODEL;
  const float scale = 0.08838834764831845f;  // 1/sqrt(128)

  const float* Kb = QKV + (size_t)(b * SEQ) * STR + D_MODEL + h * 128;
  for (int idx = threadIdx.x; idx < SEQ * 16; idx += 256) {
    int j = idx >> 4, dq = (idx & 15) << 2;
    float4 a = *(const float4*)(Kb + (size_t)j * STR + dq);
    float4 bb = *(const float4*)(Kb + (size_t)j * STR + dq + 64);
    float4 c4 = *(const float4*)(cosT + j * 64 + dq);
    float4 s4 = *(const float4*)(sinT + j * 64 + dq);
    float* kr = ks + j * 132 + dq;
    kr[0] = a.x*c4.x - bb.x*s4.x; kr[1] = a.y*c4.y - bb.y*s4.y;
    kr[2] = a.z*c4.z - bb.z*s4.z; kr[3] = a.w*c4.w - bb.w*s4.w;
    kr[64] = bb.x*c4.x + a.x*s4.x; kr[65] = bb.y*c4.y + a.y*s4.y;
    kr[66] = bb.z*c4.z + a.z*s4.z; kr[67] = bb.w*c4.w + a.w*s4.w;
  }
  const float* Qb = QKV + (size_t)(b * SEQ) * STR + h * 128;
  for (int idx = threadIdx.x; idx < ATILE * 16; idx += 256) {
    int il = idx >> 4, dq = (idx & 15) << 2;
    int i = it * ATILE + il;
    if (i < SEQ) {
      float4 a = *(const float4*)(Qb + (size_t)i * STR + dq);
      float4 bb = *(const float4*)(Qb + (size_t)i * STR + dq + 64);
      float4 c4 = *(const float4*)(cosT + i * 64 + dq);
      float4 s4 = *(const float4*)(sinT + i * 64 + dq);
      float* qr = qs + il * 132 + dq;
      qr[0] = a.x*c4.x - bb.x*s4.x; qr[1] = a.y*c4.y - bb.y*s4.y;
      qr[2] = a.z*c4.z - bb.z*s4.z; qr[3] = a.w*c4.w - bb.w*s4.w;
      qr[64] = bb.x*c4.x + a.x*s4.x; qr[65] = bb.y*c4.y + a.y*s4.y;
      qr[66] = bb.z*c4.z + a.z*s4.z; qr[67] = bb.w*c4.w + a.w*s4.w;
    }
  }
  for (int j = threadIdx.x; j < SEQ; j += 256) am[j] = amask[b * SEQ + j];
  __syncthreads();

  int wave = threadIdx.x >> 6, lane = threadIdx.x & 63;
  #pragma unroll
  for (int r = 0; r < 4; ++r) {
    int il = wave * 4 + r;
    int i = it * ATILE + il;
    if (i < SEQ) {
      const float4* qr = (const float4*)(qs + il * 132);
      int j1 = lane, j2 = lane + 64;
      float v1 = -1e9f, v2 = -1e9f;
      if (j1 <= i && am[j1]) {
        const float4* kr = (const float4*)(ks + j1 * 132);
        float s = 0.f;
        #pragma unroll 8
        for (int d = 0; d < 32; ++d) {
          float4 a = qr[d], c = kr[d];
          s += a.x*c.x + a.y*c.y + a.z*c.z + a.w*c.w;
        }
        v1 = s * scale;
      }
      if (j2 < SEQ && j2 <= i && am[j2]) {
        const float4* kr = (const float4*)(ks + j2 * 132);
        float s = 0.f;
        #pragma unroll 8
        for (int d = 0; d < 32; ++d) {
          float4 a = qr[d], c = kr[d];
          s += a.x*c.x + a.y*c.y + a.z*c.z + a.w*c.w;
        }
        v2 = s * scale;
      }
      float mx = fmaxf(v1, v2);
      #pragma unroll
      for (int off = 32; off; off >>= 1) mx = fmaxf(mx, __shfl_xor(mx, off));
      float e1 = __expf(v1 - mx);
      float e2 = (j2 < SEQ) ? __expf(v2 - mx) : 0.f;
      float sum = e1 + e2;
      #pragma unroll
      for (int off = 32; off; off >>= 1) sum += __shfl_xor(sum, off);
      float inv = 1.0f / sum;
      sc[il * 80 + j1] = e1 * inv;
      if (j2 < SEQ) sc[il * 80 + j2] = e2 * inv;
    }
  }
  __syncthreads();

  const float* Vbase = QKV + (size_t)(b * SEQ) * STR + 2 * D_MODEL + h * 128;
  for (int idx = threadIdx.x; idx < ATILE * 32; idx += 256) {
    int il = idx >> 5, d4 = (idx & 31) << 2;
    int i = it * ATILE + il;
    if (i >= SEQ) continue;
    float4 acc = {0.f, 0.f, 0.f, 0.f};
    const float* sr = sc + il * 80;
    for (int j = 0; j < SEQ; ++j) {
      float pp = sr[j];
      float4 v = *(const float4*)(Vbase + (size_t)j * STR + d4);
      acc.x += pp * v.x; acc.y += pp * v.y; acc.z += pp * v.z; acc.w += pp * v.w;
    }
    unsigned short* op = O + (size_t)(b * SEQ + i) * D_MODEL + h * 128 + d4;
    op[0] = f2b(acc.x); op[1] = f2b(acc.y); op[2] = f2b(acc.z); op[3] = f2b(acc.w);
  }
}

__global__ void embed_gather(const float* __restrict__ E, const int* __restrict__ ids,
                             float* __restrict__ H)
{
  size_t idx = (size_t)blockIdx.x * 256 + threadIdx.x;
  int m = (int)(idx / D_MODEL);
  int n = (int)(idx % D_MODEL);
  H[idx] = E[(size_t)ids[m] * D_MODEL + n];
}

__global__ __launch_bounds__(256) void final_k(
    const float* __restrict__ H, const int* __restrict__ amask,
    const float* __restrict__ W, float* __restrict__ out)
{
  int b = blockIdx.x;
  __shared__ int len;
  if (threadIdx.x == 0) {
    int s = 0;
    for (int j = 0; j < SEQ; ++j) s += amask[b * SEQ + j];
    len = s - 1;
  }
  __syncthreads();
  const float* hr = H + ((size_t)(b * SEQ + len) * D_MODEL);
  float s = 0.f;
  for (int i = threadIdx.x; i < D_MODEL; i += 256) { float v = hr[i]; s += v * v; }
  __shared__ float red[4];
  #pragma unroll
  for (int off = 32; off; off >>= 1) s += __shfl_down(s, off, 64);
  if ((threadIdx.x & 63) == 0) red[threadIdx.x >> 6] = s;
  __syncthreads();
  float tot = red[0] + red[1] + red[2] + red[3];
  float inv = rsqrtf(tot / (float)D_MODEL + 1e-6f);
  for (int i = threadIdx.x; i < D_MODEL; i += 256)
    out[(size_t)b * D_MODEL + i] = hr[i] * inv * W[i];
}

// ---------------------------------------------------------------------------
extern "C" void kernel_launch(void* const* d_in, const int* in_sizes, int n_in,
                              void* d_out, int out_size, void* d_ws, size_t ws_size,
                              hipStream_t stream) {
  const int*   ids     = (const int*)d_in[0];
  const int*   amask   = (const int*)d_in[1];
  const float* embed   = (const float*)d_in[2];
  const float* ln_attn = (const float*)d_in[3];
  const float* ln_mlp  = (const float*)d_in[4];
  const float* ln_fin  = (const float*)d_in[5];
  const int*   qkvC    = (const int*)d_in[6];
  const float* qkvS    = (const float*)d_in[7];
  const float* qkvA    = (const float*)d_in[8];
  const float* qkvB    = (const float*)d_in[9];
  const int*   oC      = (const int*)d_in[10];
  const float* oS      = (const float*)d_in[11];
  const float* oA      = (const float*)d_in[12];
  const float* oB      = (const float*)d_in[13];
  const int*   guC     = (const int*)d_in[14];
  const float* guS     = (const float*)d_in[15];
  const float* guA     = (const float*)d_in[16];
  const float* guB     = (const float*)d_in[17];
  const int*   dnC     = (const int*)d_in[18];
  const float* dnS     = (const float*)d_in[19];
  const float* dnA     = (const float*)d_in[20];
  const float* dnB     = (const float*)d_in[21];
  float* out = (float*)d_out;

  const int M = M_TOK, Mp = M_PAD, D = D_MODEL, F = F_FFN, R = LRANK;
  float* p = (float*)d_ws;
  float* h    = p; p += (size_t)Mp * D;
  float* qkv  = p; p += (size_t)Mp * 3 * D;
  float* t    = p; p += (size_t)Mp * 48;
  float* cosT = p; p += SEQ * 64;
  float* sinT = p; p += SEQ * 64;
  unsigned short* xbf = (unsigned short*)p; p += (size_t)Mp * D / 2;
  unsigned short* gbf = (unsigned short*)p; p += (size_t)Mp * F / 2;
  unsigned short* wQ = (unsigned short*)p; p += (size_t)3 * D * D / 2;
  unsigned short* wO = (unsigned short*)p; p += (size_t)D * D / 2;
  unsigned short* wG = (unsigned short*)p; p += (size_t)2 * F * D / 2;
  unsigned short* wD = (unsigned short*)p; p += (size_t)D * F / 2;

  rope_table<<<(SEQ*64 + 63)/64, 64, 0, stream>>>(cosT, sinT);
  embed_gather<<<(M * D)/256, 256, 0, stream>>>(embed, ids, h);
  mat_w<<<2048, 256, 0, stream>>>(qkvC, qkvS, wQ, D, (long)3*D*D/8, 0);

  const int mb = Mp / 128;
  const int Gqkv = mb * (3*D/128);        // 480
  const int Go   = mb * (D/128) * 4;      // 640 (splitk 4)
  const int Ggu  = mb * (2*F/128);        // 1280
  const int Gdn  = mb * (D/128) * 4;      // 640 (splitk 4)
  const long oT8   = (long)D * D / 8;
  const long guT8  = (long)2 * F * D / 8;
  const long guA8  = guT8 * 6 / 8;        // qkv-carried share (800 spare blocks)
  const long dnT8  = (long)D * F / 8;
  const long qkvT8 = (long)3 * D * D / 8;

  for (int l = 0; l < NLAYER; ++l) {
    // ---- attention ----
    rmsnorm_k<<<M, 256, 0, stream>>>(h, ln_attn + (size_t)l * D, xbf, D);
    lora1<<<dim3(M/4, 3), 256, 0, stream>>>(xbf, qkvA + (size_t)l*3*R*D, t, D);
    // qkv GEMM (+fused LoRA); carries gu-w first 6/8 (800 blocks)
    gemm_bf<<<Gqkv + 800, 256, 0, stream>>>(
        xbf, wQ, qkv, mb, 3*D, D, 0, 1,
        t, qkvB + (size_t)l*3*D*R, 11, 48, 0, nullptr,
        guC + (size_t)l*2*F*D, guS + (size_t)l*2*F*(D/64), wG, D, 0, guA8, 1, 800,
        nullptr, nullptr, nullptr, D, 0, 0, 0, Gqkv);
    // attn (+ carry row y==NT_ATT: o weights)
    attn_k<<<dim3(BATCH*NHEAD, NT_ATT + 1), 256, 0, stream>>>(
        qkv, amask, cosT, sinT, xbf,
        oC + (size_t)l*D*D, oS + (size_t)l*D*(D/64), wO, oT8);
    lora1<<<dim3(M/4, 1), 256, 0, stream>>>(xbf, oA + (size_t)l*R*D, t, D);
    // o GEMM (splitk4, fused LoRA slice0); carries remaining 2/8 of gu-w
    gemm_bf<<<Go + 512, 256, 0, stream>>>(
        xbf, wO, h, mb, D, D, 1, 4,
        t, oB + (size_t)l*D*R, 11, 16, 0, nullptr,
        guC + (size_t)l*2*F*D, guS + (size_t)l*2*F*(D/64), wG, D,
        guA8, guT8 - guA8, 1, 512,
        nullptr, nullptr, nullptr, D, 0, 0, 0, Go);

    // ---- MLP ----
    rmsnorm_k<<<M, 256, 0, stream>>>(h, ln_mlp + (size_t)l * D, xbf, D);
    lora1<<<dim3(M/4, 2), 256, 0, stream>>>(xbf, guA + (size_t)l*2*R*D, t, D);
    // gu GEMM (GUMODE); carries down-w (512 blks, retire-tail)
    gemm_bf<<<Ggu + 512, 256, 0, stream>>>(
        xbf, wG, nullptr, mb, 2*F, D, 0, 1,
        t, guB + (size_t)l*2*F*R, 0, 32, 1, gbf,
        dnC + (size_t)l*D*F, dnS + (size_t)l*D*(F/64), wD, F, 0, dnT8, 0, 512,
        nullptr, nullptr, nullptr, D, 0, 0, 0, Ggu);
    lora1<<<dim3(M/4, 1), 256, 0, stream>>>(gbf, dnA + (size_t)l*R*F, t, F);
    // down GEMM (splitk4, fused LoRA slice0); carries next-layer qkv-w
    if (l + 1 < NLAYER) {
      gemm_bf<<<Gdn + 512, 256, 0, stream>>>(
          gbf, wD, h, mb, D, F, 1, 4,
          t, dnB + (size_t)l*D*R, 11, 16, 0, nullptr,
          qkvC + (size_t)(l+1)*3*D*D, qkvS + (size_t)(l+1)*3*D*(D/64),
          wQ, D, 0, qkvT8, 0, 512,
          nullptr, nullptr, nullptr, D, 0, 0, 0, Gdn);
    } else {
      gemm_bf<<<Gdn, 256, 0, stream>>>(
          gbf, wD, h, mb, D, F, 1, 4,
          t, dnB + (size_t)l*D*R, 11, 16, 0, nullptr,
          nullptr, nullptr, nullptr, D, 0, 0, 0, 0,
          nullptr, nullptr, nullptr, D, 0, 0, 0, Gdn);
    }
  }
  final_k<<<BATCH, 256, 0, stream>>>(h, amask, ln_fin, out);
}